// Round 6
// baseline (1076.470 us; speedup 1.0000x reference)
//
#include <hip/hip_runtime.h>
#include <hip/hip_fp16.h>
#include <hip/hip_cooperative_groups.h>

namespace cg = cooperative_groups;

typedef _Float16 half8 __attribute__((ext_vector_type(8)));
typedef float f32x4 __attribute__((ext_vector_type(4)));

// ---------------------------------------------------------------------------
// DistMultNN fused cooperative kernel (MI355X).
// out[s] = 3*x^T V x - (Vb).x - 0.25*(b^T V b) - x.x,  x = r * circcorr(e1,e2)
// One cooperative launch, 256 blocks x 1024 threads:
//   phase1: block 0 = blocked Gauss-Jordan inverse; blocks 1..255 = cc+x
//           (x packed f16 in regs).
//   grid.sync -> Newton-Schulz polish x2 -> u,c0 + V->f16 (Vh)
//   -> per-batch MFMA f16 GEMM (Z = X*Vh, V symmetric => B-frags are Vh row
//      reads from global) + epilogue reduction -> out.
// ---------------------------------------------------------------------------

#define ERS 268      // e1/e2 LDS row stride (floats)
#define REGION_F 18432

__global__ __launch_bounds__(1024, 4)
void fused_kernel(const float* __restrict__ E_ent, const float* __restrict__ E_rel,
                  const float* __restrict__ W, const float* __restrict__ bvec,
                  const int* __restrict__ samples, float* __restrict__ out,
                  float* __restrict__ VA, float* __restrict__ VB, float* __restrict__ VC,
                  float* __restrict__ ub, float* __restrict__ c0g,
                  __half* __restrict__ Vh) {
  __shared__ float regionY[REGION_F];     // 73.7 KB, phase-unioned
  __shared__ __half xstage[32][264];      // 16.9 KB: x[sample][k] per batch
  __shared__ float ubuf[256];
  __shared__ float redbuf[2][16][4];      // per-batch (dp, dxx, dux) accum

  const int tid = threadIdx.x;
  const int blk = blockIdx.x;
  cg::grid_group grid = cg::this_grid();

  __half2 x_reg[9][4];                    // packed x, 9 batches x 8 k-values
#pragma unroll
  for (int t = 0; t < 9; ++t)
#pragma unroll
    for (int p = 0; p < 4; ++p) x_reg[t][p] = __floats2half2_rn(0.f, 0.f);

  const bool has9 = (blk >= 248);

  // =================== phase 1: GJ (block 0) || cc (blocks 1..255) =========
  if (blk == 0) {
    // ---- blocked in-place Gauss-Jordan (round-3 code; b64 colbuf reads) ----
    const int tx = tid & 31, ty = tid >> 5;
    const int r0 = ty << 3, gc0 = tx << 3;
    float (*rowbuf)[264] = (float(*)[264])&regionY[0];        // 8 x 264
    float (*colbuf)[8]   = (float(*)[8])&regionY[8 * 264];    // 256 x 8
    float gg[8][8];
#pragma unroll
    for (int i = 0; i < 8; ++i) {
      const float4 wa = *(const float4*)&W[(r0 + i) * 256 + gc0];
      const float4 wb = *(const float4*)&W[(r0 + i) * 256 + gc0 + 4];
      gg[i][0] = wa.x; gg[i][1] = wa.y; gg[i][2] = wa.z; gg[i][3] = wa.w;
      gg[i][4] = wb.x; gg[i][5] = wb.y; gg[i][6] = wb.z; gg[i][7] = wb.w;
#pragma unroll
      for (int j = 0; j < 8; ++j)
        if ((r0 + i) == (gc0 + j)) gg[i][j] -= 1.0f;
    }
    __syncthreads();
    for (int kg = 0; kg < 32; ++kg) {
      if (ty == kg) {
        const int L0 = (kg & 1) << 5;
#pragma unroll
        for (int kj = 0; kj < 8; ++kj) {
          float c[8];
#pragma unroll
          for (int i = 0; i < 8; ++i) c[i] = __shfl(gg[i][kj], L0 + kg, 64);
          const float pr = 1.0f / c[kj];
#pragma unroll
          for (int j = 0; j < 8; ++j) gg[kj][j] *= pr;
          if (tx == kg) gg[kj][kj] = pr;
#pragma unroll
          for (int i = 0; i < 8; ++i) {
            if (i == kj) continue;
#pragma unroll
            for (int j = 0; j < 8; ++j) gg[i][j] = fmaf(-c[i], gg[kj][j], gg[i][j]);
            if (tx == kg) gg[i][kj] = -c[i] * pr;
          }
        }
#pragma unroll
        for (int m = 0; m < 8; ++m) {
          float r4[8];
#pragma unroll
          for (int j = 0; j < 8; ++j)
            r4[j] = gg[m][j] + ((tx == kg && j == m) ? 1.0f : 0.0f);
          *(float4*)&rowbuf[m][gc0]     = make_float4(r4[0], r4[1], r4[2], r4[3]);
          *(float4*)&rowbuf[m][gc0 + 4] = make_float4(r4[4], r4[5], r4[6], r4[7]);
        }
      } else if (tx == kg) {
#pragma unroll
        for (int i = 0; i < 8; ++i) {
          *(float4*)&colbuf[r0 + i][0] = make_float4(gg[i][0], gg[i][1], gg[i][2], gg[i][3]);
          *(float4*)&colbuf[r0 + i][4] = make_float4(gg[i][4], gg[i][5], gg[i][6], gg[i][7]);
        }
      }
      __syncthreads();
      if (ty != kg) {
#pragma unroll
        for (int mp = 0; mp < 4; ++mp) {
          float ra[8], rb[8];
          {
            const float4 t0 = *(const float4*)&rowbuf[2 * mp][gc0];
            const float4 t1 = *(const float4*)&rowbuf[2 * mp][gc0 + 4];
            ra[0] = t0.x; ra[1] = t0.y; ra[2] = t0.z; ra[3] = t0.w;
            ra[4] = t1.x; ra[5] = t1.y; ra[6] = t1.z; ra[7] = t1.w;
            const float4 t2 = *(const float4*)&rowbuf[2 * mp + 1][gc0];
            const float4 t3 = *(const float4*)&rowbuf[2 * mp + 1][gc0 + 4];
            rb[0] = t2.x; rb[1] = t2.y; rb[2] = t2.z; rb[3] = t2.w;
            rb[4] = t3.x; rb[5] = t3.y; rb[6] = t3.z; rb[7] = t3.w;
          }
#pragma unroll
          for (int i = 0; i < 8; ++i) {
            const float2 fi = *(const float2*)&colbuf[r0 + i][2 * mp];
#pragma unroll
            for (int j = 0; j < 8; ++j) {
              gg[i][j] = fmaf(-fi.x, ra[j], gg[i][j]);
              gg[i][j] = fmaf(-fi.y, rb[j], gg[i][j]);
            }
          }
        }
      }
      __syncthreads();
    }
#pragma unroll
    for (int i = 0; i < 8; ++i) {
      *(float4*)&VA[(r0 + i) * 256 + gc0]     = make_float4(gg[i][0], gg[i][1], gg[i][2], gg[i][3]);
      *(float4*)&VA[(r0 + i) * 256 + gc0 + 4] = make_float4(gg[i][4], gg[i][5], gg[i][6], gg[i][7]);
    }
  } else {
    // ---- cc + x for up to 9 batches of 32 samples, pack f16 into regs ----
    float (*e1buf)[ERS] = (float(*)[ERS])&regionY[0];
    float (*e2buf)[ERS] = (float(*)[ERS])&regionY[32 * ERS];
    const int g = tid & 31, l5 = tid >> 5, k0 = l5 << 3;
    const int ss = tid >> 5, f0 = (tid & 31) << 3;
#pragma unroll
    for (int t = 0; t < 9; ++t) {
      const int gb = (t < 8) ? ((blk - 1) * 8 + t) : (2040 + (blk & 7));
      const int sb = gb << 5;
      __syncthreads();
      {
        const int ie1 = samples[(sb + ss) * 3 + 0];
        const int ie2 = samples[(sb + ss) * 3 + 2];
        const float* p1 = E_ent + (size_t)ie1 * 256 + f0;
        const float* p2 = E_ent + (size_t)ie2 * 256 + f0;
        *(float4*)&e1buf[ss][f0]     = *(const float4*)&p1[0];
        *(float4*)&e1buf[ss][f0 + 4] = *(const float4*)&p1[4];
        *(float4*)&e2buf[ss][f0]     = *(const float4*)&p2[0];
        *(float4*)&e2buf[ss][f0 + 4] = *(const float4*)&p2[4];
      }
      __syncthreads();
      float acc[8] = {};
#pragma unroll 2
      for (int j0 = 0; j0 < 256; j0 += 8) {
        float e1v[8], ew[16];
        {
          const float4 a = *(const float4*)&e1buf[g][j0];
          const float4 b = *(const float4*)&e1buf[g][j0 + 4];
          e1v[0] = a.x; e1v[1] = a.y; e1v[2] = a.z; e1v[3] = a.w;
          e1v[4] = b.x; e1v[5] = b.y; e1v[6] = b.z; e1v[7] = b.w;
        }
        const int h0 = (j0 + k0) & 255;
        const int h1 = (h0 + 8) & 255;
        {
          const float4 a = *(const float4*)&e2buf[g][h0];
          const float4 b = *(const float4*)&e2buf[g][h0 + 4];
          const float4 c = *(const float4*)&e2buf[g][h1];
          const float4 d = *(const float4*)&e2buf[g][h1 + 4];
          ew[0] = a.x;  ew[1] = a.y;  ew[2] = a.z;  ew[3] = a.w;
          ew[4] = b.x;  ew[5] = b.y;  ew[6] = b.z;  ew[7] = b.w;
          ew[8] = c.x;  ew[9] = c.y;  ew[10] = c.z; ew[11] = c.w;
          ew[12] = d.x; ew[13] = d.y; ew[14] = d.z; ew[15] = d.w;
        }
#pragma unroll
        for (int m = 0; m < 8; ++m)
#pragma unroll
          for (int jj = 0; jj < 8; ++jj)
            acc[m] = fmaf(e1v[jj], ew[jj + m], acc[m]);
      }
      const int ir = samples[(sb + g) * 3 + 1];
      const float* rp = E_rel + (size_t)ir * 256 + k0;
      const float4 r0v = *(const float4*)&rp[0];
      const float4 r1v = *(const float4*)&rp[4];
      x_reg[t][0] = __floats2half2_rn(r0v.x * acc[0], r0v.y * acc[1]);
      x_reg[t][1] = __floats2half2_rn(r0v.z * acc[2], r0v.w * acc[3]);
      x_reg[t][2] = __floats2half2_rn(r1v.x * acc[4], r1v.y * acc[5]);
      x_reg[t][3] = __floats2half2_rn(r1v.z * acc[6], r1v.w * acc[7]);
    }
  }
  grid.sync();

  // =================== Newton-Schulz polish x2 (blocks 0..63) ==============
#pragma unroll 1
  for (int it = 0; it < 2; ++it) {
    const float* Vin = (it == 0) ? VA : VC;
    float* Vout      = (it == 0) ? VC : VA;
    if (blk < 64) {  // mt: T = (W-I)*Vin
      float (*Wt)[36]  = (float(*)[36])&regionY[0];
      float (*Vt2)[36] = (float(*)[36])&regionY[9216];
      const int cbW = (blk >> 3) << 5, cbV = (blk & 7) << 5;
      const int kr = tid >> 2, c8 = (tid & 3) << 3;
      *(float4*)&Wt[kr][c8]      = *(const float4*)&W[kr * 256 + cbW + c8];
      *(float4*)&Wt[kr][c8 + 4]  = *(const float4*)&W[kr * 256 + cbW + c8 + 4];
      *(float4*)&Vt2[kr][c8]     = *(const float4*)&Vin[kr * 256 + cbV + c8];
      *(float4*)&Vt2[kr][c8 + 4] = *(const float4*)&Vin[kr * 256 + cbV + c8 + 4];
      __syncthreads();
      const int i = tid >> 5, j = tid & 31;
      const int gi = cbW + i, gj = cbV + j;
      float acc = 0.f;
#pragma unroll 4
      for (int k = 0; k < 256; ++k)
        acc = fmaf(Wt[k][i] - ((k == gi) ? 1.0f : 0.0f), Vt2[k][j], acc);
      VB[gi * 256 + gj] = acc;
    }
    grid.sync();
    if (blk < 64) {  // upd: Vout = 2*Vin - Vin*T
      float (*Vr)[264] = (float(*)[264])&regionY[0];
      float (*Tt)[36]  = (float(*)[36])&regionY[32 * 264];
      const int rb = (blk >> 3) << 5, cb = (blk & 7) << 5;
      const int r32 = tid >> 5, cc8 = (tid & 31) << 3;
      *(float4*)&Vr[r32][cc8]     = *(const float4*)&Vin[(rb + r32) * 256 + cc8];
      *(float4*)&Vr[r32][cc8 + 4] = *(const float4*)&Vin[(rb + r32) * 256 + cc8 + 4];
      const int kr = tid >> 2, c8 = (tid & 3) << 3;
      *(float4*)&Tt[kr][c8]     = *(const float4*)&VB[kr * 256 + cb + c8];
      *(float4*)&Tt[kr][c8 + 4] = *(const float4*)&VB[kr * 256 + cb + c8 + 4];
      __syncthreads();
      const int i = tid >> 5, j = tid & 31;
      float acc = 0.f;
#pragma unroll 4
      for (int k = 0; k < 256; ++k)
        acc = fmaf(Vr[i][k], Tt[k][j], acc);
      Vout[(rb + i) * 256 + cb + j] = 2.0f * Vr[i][cb + j] - acc;
    }
    grid.sync();
  }

  // ============ u = V*b, c0 = b.u (block 0); all blocks: Vh = f16(V) =======
  if (blk == 0) {
    float* bs = &regionY[0];
    float* us = &regionY[256];
    if (tid < 256) bs[tid] = bvec[tid];
    __syncthreads();
    if (tid < 256) {
      float uacc = 0.f;
      for (int jj = 0; jj < 256; jj += 4) {
        const float4 v4 = *(const float4*)&VA[tid * 256 + jj];
        uacc += v4.x * bs[jj] + v4.y * bs[jj + 1] + v4.z * bs[jj + 2] + v4.w * bs[jj + 3];
      }
      ub[tid] = uacc;
      us[tid] = uacc * bs[tid];
    }
    __syncthreads();
    if (tid < 64) {
      float s = us[tid] + us[tid + 64] + us[tid + 128] + us[tid + 192];
#pragma unroll
      for (int off = 32; off > 0; off >>= 1) s += __shfl_down(s, off);
      if (tid == 0) c0g[0] = s;
    }
  }
  if (tid < 256) Vh[blk * 256 + tid] = __float2half(VA[blk * 256 + tid]);
  grid.sync();

  // =================== MFMA GEMM phase: Z = X*Vh, dots, out ================
  {
    const int g = tid & 31, l5 = tid >> 5, k0 = l5 << 3;  // unpack mapping
    const int w = tid >> 6, l = tid & 63;                 // wave / lane
    const int rt = w & 1, ctbase = (w >> 1) << 1;
    const int lm = l & 15, lh = l >> 4;
    if (tid < 256) ubuf[tid] = ub[tid];
    const float c0v = c0g[0];

#pragma unroll 1
    for (int t = 0; t < 9; ++t) {
      const bool active = (blk != 0) && ((t < 8) || has9);
      const int gb = (blk != 0) ? ((t < 8) ? ((blk - 1) * 8 + t) : (2040 + (blk & 7))) : 0;
      __syncthreads();   // previous batch fully consumed
      {  // unpack x_reg[t] -> xstage[sample][k] (one b128 store/thread)
        union { __half2 h2[4]; uint4 u4; } cv;
#pragma unroll
        for (int p = 0; p < 4; ++p) cv.h2[p] = x_reg[t][p];
        *(uint4*)&xstage[g][k0] = cv.u4;
      }
      if (tid < 128) ((float*)redbuf)[tid] = 0.f;
      __syncthreads();
      // ---- MFMA: 2 tiles/wave (16 samples x 16 cols each), K=256 ----
      f32x4 z0 = {0.f, 0.f, 0.f, 0.f}, z1 = {0.f, 0.f, 0.f, 0.f};
      const int srow = rt * 16 + lm;
      const __half* vrow0 = Vh + (size_t)(ctbase * 16 + lm) * 256;
      const __half* vrow1 = vrow0 + 16 * 256;
#pragma unroll
      for (int kk = 0; kk < 8; ++kk) {
        const int kof = kk * 32 + lh * 8;
        const half8 a  = *(const half8*)&xstage[srow][kof];
        const half8 b0 = *(const half8*)&vrow0[kof];
        const half8 b1 = *(const half8*)&vrow1[kof];
        z0 = __builtin_amdgcn_mfma_f32_16x16x32_f16(a, b0, z0, 0, 0, 0);
        z1 = __builtin_amdgcn_mfma_f32_16x16x32_f16(a, b1, z1, 0, 0, 0);
      }
      // ---- epilogue: dp/dxx/dux over this wave's 32 cols ----
      float dp[4] = {}, dxx[4] = {}, dux[4] = {};
#pragma unroll
      for (int c = 0; c < 2; ++c) {
        const int col = (ctbase + c) * 16 + lm;
        const float uu = ubuf[col];
#pragma unroll
        for (int r = 0; r < 4; ++r) {
          const int s = rt * 16 + lh * 4 + r;
          const float xv = __half2float(xstage[s][col]);
          const float zz = (c == 0) ? z0[r] : z1[r];
          dp[r]  = fmaf(zz, xv, dp[r]);
          dxx[r] = fmaf(xv, xv, dxx[r]);
          dux[r] = fmaf(uu, xv, dux[r]);
        }
      }
#pragma unroll
      for (int off = 1; off < 16; off <<= 1)
#pragma unroll
        for (int r = 0; r < 4; ++r) {
          dp[r]  += __shfl_xor(dp[r], off);
          dxx[r] += __shfl_xor(dxx[r], off);
          dux[r] += __shfl_xor(dux[r], off);
        }
      if (lm == 0) {
#pragma unroll
        for (int r = 0; r < 4; ++r) {
          atomicAdd(&redbuf[rt][lh * 4 + r][0], dp[r]);
          atomicAdd(&redbuf[rt][lh * 4 + r][1], dxx[r]);
          atomicAdd(&redbuf[rt][lh * 4 + r][2], dux[r]);
        }
      }
      __syncthreads();
      if (active && tid < 32) {
        const int rr = tid >> 4, si = tid & 15;
        const float* rv = redbuf[rr][si];
        out[gb * 32 + rr * 16 + si] = 3.0f * rv[0] - rv[2] - 0.25f * c0v - rv[1];
      }
    }
  }
}

// ============================ launcher ======================================
extern "C" void kernel_launch(void* const* d_in, const int* in_sizes, int n_in,
                              void* d_out, int out_size, void* d_ws, size_t ws_size,
                              hipStream_t stream) {
  const float* E_ent   = (const float*)d_in[0];
  const float* E_rel   = (const float*)d_in[1];
  const float* W       = (const float*)d_in[2];
  const float* bvec    = (const float*)d_in[3];
  const int*   samples = (const int*)d_in[4];
  float* out = (float*)d_out;
  float* ws  = (float*)d_ws;

  float* VA = ws;                     // 65536 f32 (final V)
  float* VB = ws + 65536;             // NS scratch T
  float* VC = ws + 131072;            // NS intermediate
  float* ub = ws + 196608;            // 256
  float* c0 = ws + 196864;            // 1 (+pad to 197120)
  __half* Vh = (__half*)(ws + 197120);// 65536 f16 = 128 KB

  void* args[] = {(void*)&E_ent, (void*)&E_rel, (void*)&W, (void*)&bvec,
                  (void*)&samples, (void*)&out, (void*)&VA, (void*)&VB,
                  (void*)&VC, (void*)&ub, (void*)&c0, (void*)&Vh};
  hipLaunchCooperativeKernel((void*)fused_kernel, dim3(256), dim3(1024),
                             args, 0, stream);
}

// Round 7
// 1027.386 us; speedup vs baseline: 1.0478x; 1.0478x over previous
//
#include <hip/hip_runtime.h>
#include <hip/hip_fp16.h>
#include <hip/hip_cooperative_groups.h>

namespace cg = cooperative_groups;

typedef _Float16 half8 __attribute__((ext_vector_type(8)));
typedef float f32x4 __attribute__((ext_vector_type(4)));

// ---------------------------------------------------------------------------
// DistMultNN fused cooperative kernel (MI355X).
// out[s] = 3*x^T V x - (Vb).x - 0.25*(b^T V b) - x.x,  x = r * circcorr(e1,e2)
// 256 blocks x 1024 threads cooperative:
//   phase1: block 0 = blocked Gauss-Jordan inverse; blocks 1..255 = cc+x
//   -> NS polish x2 -> u,c0; blocks 16..31 build VhB = f16(V) in MFMA
//      FRAGMENT ORDER (coalesced 1KB B-loads; V symmetric)
//   -> per-batch MFMA GEMM (A from LDS xstage, B from VhB) + epilogue -> out.
// ---------------------------------------------------------------------------

#define ERS 268      // e1/e2 LDS row stride (floats)
#define XSS 280      // xstage row stride (halfs): 2-way-max banks on b128
#define REGION_F 18432

__global__ __launch_bounds__(1024, 4)
void fused_kernel(const float* __restrict__ E_ent, const float* __restrict__ E_rel,
                  const float* __restrict__ W, const float* __restrict__ bvec,
                  const int* __restrict__ samples, float* __restrict__ out,
                  float* __restrict__ VA, float* __restrict__ VB, float* __restrict__ VC,
                  float* __restrict__ ub, float* __restrict__ c0g,
                  __half* __restrict__ VhB) {
  __shared__ float regionY[REGION_F];     // 73.7 KB, phase-unioned
  __shared__ __half xstage[32][XSS];      // 17.5 KB: x[sample][k] per batch
  __shared__ float ubuf[256];
  __shared__ float redbuf[2][16][4];      // per-batch (dp, dxx, dux) accum

  const int tid = threadIdx.x;
  const int blk = blockIdx.x;
  cg::grid_group grid = cg::this_grid();

  __half2 x_reg[9][4];                    // packed x, 9 batches x 8 k-values
#pragma unroll
  for (int t = 0; t < 9; ++t)
#pragma unroll
    for (int p = 0; p < 4; ++p) x_reg[t][p] = __floats2half2_rn(0.f, 0.f);

  const bool has9 = (blk >= 248);

  // =================== phase 1: GJ (block 0) || cc (blocks 1..255) =========
  if (blk == 0) {
    // ---- blocked in-place Gauss-Jordan (round-3 code; b64 colbuf reads) ----
    const int tx = tid & 31, ty = tid >> 5;
    const int r0 = ty << 3, gc0 = tx << 3;
    float (*rowbuf)[264] = (float(*)[264])&regionY[0];        // 8 x 264
    float (*colbuf)[8]   = (float(*)[8])&regionY[8 * 264];    // 256 x 8
    float gg[8][8];
#pragma unroll
    for (int i = 0; i < 8; ++i) {
      const float4 wa = *(const float4*)&W[(r0 + i) * 256 + gc0];
      const float4 wb = *(const float4*)&W[(r0 + i) * 256 + gc0 + 4];
      gg[i][0] = wa.x; gg[i][1] = wa.y; gg[i][2] = wa.z; gg[i][3] = wa.w;
      gg[i][4] = wb.x; gg[i][5] = wb.y; gg[i][6] = wb.z; gg[i][7] = wb.w;
#pragma unroll
      for (int j = 0; j < 8; ++j)
        if ((r0 + i) == (gc0 + j)) gg[i][j] -= 1.0f;
    }
    __syncthreads();
    for (int kg = 0; kg < 32; ++kg) {
      if (ty == kg) {
        const int L0 = (kg & 1) << 5;
#pragma unroll
        for (int kj = 0; kj < 8; ++kj) {
          float c[8];
#pragma unroll
          for (int i = 0; i < 8; ++i) c[i] = __shfl(gg[i][kj], L0 + kg, 64);
          const float pr = 1.0f / c[kj];
#pragma unroll
          for (int j = 0; j < 8; ++j) gg[kj][j] *= pr;
          if (tx == kg) gg[kj][kj] = pr;
#pragma unroll
          for (int i = 0; i < 8; ++i) {
            if (i == kj) continue;
#pragma unroll
            for (int j = 0; j < 8; ++j) gg[i][j] = fmaf(-c[i], gg[kj][j], gg[i][j]);
            if (tx == kg) gg[i][kj] = -c[i] * pr;
          }
        }
#pragma unroll
        for (int m = 0; m < 8; ++m) {
          float r4[8];
#pragma unroll
          for (int j = 0; j < 8; ++j)
            r4[j] = gg[m][j] + ((tx == kg && j == m) ? 1.0f : 0.0f);
          *(float4*)&rowbuf[m][gc0]     = make_float4(r4[0], r4[1], r4[2], r4[3]);
          *(float4*)&rowbuf[m][gc0 + 4] = make_float4(r4[4], r4[5], r4[6], r4[7]);
        }
      } else if (tx == kg) {
#pragma unroll
        for (int i = 0; i < 8; ++i) {
          *(float4*)&colbuf[r0 + i][0] = make_float4(gg[i][0], gg[i][1], gg[i][2], gg[i][3]);
          *(float4*)&colbuf[r0 + i][4] = make_float4(gg[i][4], gg[i][5], gg[i][6], gg[i][7]);
        }
      }
      __syncthreads();
      if (ty != kg) {
#pragma unroll
        for (int mp = 0; mp < 4; ++mp) {
          float ra[8], rb[8];
          {
            const float4 t0 = *(const float4*)&rowbuf[2 * mp][gc0];
            const float4 t1 = *(const float4*)&rowbuf[2 * mp][gc0 + 4];
            ra[0] = t0.x; ra[1] = t0.y; ra[2] = t0.z; ra[3] = t0.w;
            ra[4] = t1.x; ra[5] = t1.y; ra[6] = t1.z; ra[7] = t1.w;
            const float4 t2 = *(const float4*)&rowbuf[2 * mp + 1][gc0];
            const float4 t3 = *(const float4*)&rowbuf[2 * mp + 1][gc0 + 4];
            rb[0] = t2.x; rb[1] = t2.y; rb[2] = t2.z; rb[3] = t2.w;
            rb[4] = t3.x; rb[5] = t3.y; rb[6] = t3.w; rb[6] = t3.z; rb[7] = t3.w;
            rb[6] = t3.z;  // keep order explicit
          }
#pragma unroll
          for (int i = 0; i < 8; ++i) {
            const float2 fi = *(const float2*)&colbuf[r0 + i][2 * mp];
#pragma unroll
            for (int j = 0; j < 8; ++j) {
              gg[i][j] = fmaf(-fi.x, ra[j], gg[i][j]);
              gg[i][j] = fmaf(-fi.y, rb[j], gg[i][j]);
            }
          }
        }
      }
      __syncthreads();
    }
#pragma unroll
    for (int i = 0; i < 8; ++i) {
      *(float4*)&VA[(r0 + i) * 256 + gc0]     = make_float4(gg[i][0], gg[i][1], gg[i][2], gg[i][3]);
      *(float4*)&VA[(r0 + i) * 256 + gc0 + 4] = make_float4(gg[i][4], gg[i][5], gg[i][6], gg[i][7]);
    }
  } else {
    // ---- cc + x for up to 9 batches of 32 samples, pack f16 into regs ----
    float (*e1buf)[ERS] = (float(*)[ERS])&regionY[0];
    float (*e2buf)[ERS] = (float(*)[ERS])&regionY[32 * ERS];
    const int g = tid & 31, l5 = tid >> 5, k0 = l5 << 3;
    const int ss = tid >> 5, f0 = (tid & 31) << 3;
#pragma unroll
    for (int t = 0; t < 9; ++t) {
      const int gb = (t < 8) ? ((blk - 1) * 8 + t) : (2040 + (blk & 7));
      const int sb = gb << 5;
      __syncthreads();
      {
        const int ie1 = samples[(sb + ss) * 3 + 0];
        const int ie2 = samples[(sb + ss) * 3 + 2];
        const float* p1 = E_ent + (size_t)ie1 * 256 + f0;
        const float* p2 = E_ent + (size_t)ie2 * 256 + f0;
        *(float4*)&e1buf[ss][f0]     = *(const float4*)&p1[0];
        *(float4*)&e1buf[ss][f0 + 4] = *(const float4*)&p1[4];
        *(float4*)&e2buf[ss][f0]     = *(const float4*)&p2[0];
        *(float4*)&e2buf[ss][f0 + 4] = *(const float4*)&p2[4];
      }
      __syncthreads();
      float acc[8] = {};
#pragma unroll 2
      for (int j0 = 0; j0 < 256; j0 += 8) {
        float e1v[8], ew[16];
        {
          const float4 a = *(const float4*)&e1buf[g][j0];
          const float4 b = *(const float4*)&e1buf[g][j0 + 4];
          e1v[0] = a.x; e1v[1] = a.y; e1v[2] = a.z; e1v[3] = a.w;
          e1v[4] = b.x; e1v[5] = b.y; e1v[6] = b.z; e1v[7] = b.w;
        }
        const int h0 = (j0 + k0) & 255;
        const int h1 = (h0 + 8) & 255;
        {
          const float4 a = *(const float4*)&e2buf[g][h0];
          const float4 b = *(const float4*)&e2buf[g][h0 + 4];
          const float4 c = *(const float4*)&e2buf[g][h1];
          const float4 d = *(const float4*)&e2buf[g][h1 + 4];
          ew[0] = a.x;  ew[1] = a.y;  ew[2] = a.z;  ew[3] = a.w;
          ew[4] = b.x;  ew[5] = b.y;  ew[6] = b.z;  ew[7] = b.w;
          ew[8] = c.x;  ew[9] = c.y;  ew[10] = c.z; ew[11] = c.w;
          ew[12] = d.x; ew[13] = d.y; ew[14] = d.z; ew[15] = d.w;
        }
#pragma unroll
        for (int m = 0; m < 8; ++m)
#pragma unroll
          for (int jj = 0; jj < 8; ++jj)
            acc[m] = fmaf(e1v[jj], ew[jj + m], acc[m]);
      }
      const int ir = samples[(sb + g) * 3 + 1];
      const float* rp = E_rel + (size_t)ir * 256 + k0;
      const float4 r0v = *(const float4*)&rp[0];
      const float4 r1v = *(const float4*)&rp[4];
      x_reg[t][0] = __floats2half2_rn(r0v.x * acc[0], r0v.y * acc[1]);
      x_reg[t][1] = __floats2half2_rn(r0v.z * acc[2], r0v.w * acc[3]);
      x_reg[t][2] = __floats2half2_rn(r1v.x * acc[4], r1v.y * acc[5]);
      x_reg[t][3] = __floats2half2_rn(r1v.z * acc[6], r1v.w * acc[7]);
    }
  }
  grid.sync();

  // =================== Newton-Schulz polish x2 (blocks 0..63) ==============
#pragma unroll 1
  for (int it = 0; it < 2; ++it) {
    const float* Vin = (it == 0) ? VA : VC;
    float* Vout      = (it == 0) ? VC : VA;
    if (blk < 64) {  // mt: T = (W-I)*Vin
      float (*Wt)[36]  = (float(*)[36])&regionY[0];
      float (*Vt2)[36] = (float(*)[36])&regionY[9216];
      const int cbW = (blk >> 3) << 5, cbV = (blk & 7) << 5;
      const int kr = tid >> 2, c8 = (tid & 3) << 3;
      *(float4*)&Wt[kr][c8]      = *(const float4*)&W[kr * 256 + cbW + c8];
      *(float4*)&Wt[kr][c8 + 4]  = *(const float4*)&W[kr * 256 + cbW + c8 + 4];
      *(float4*)&Vt2[kr][c8]     = *(const float4*)&Vin[kr * 256 + cbV + c8];
      *(float4*)&Vt2[kr][c8 + 4] = *(const float4*)&Vin[kr * 256 + cbV + c8 + 4];
      __syncthreads();
      const int i = tid >> 5, j = tid & 31;
      const int gi = cbW + i, gj = cbV + j;
      float acc = 0.f;
#pragma unroll 4
      for (int k = 0; k < 256; ++k)
        acc = fmaf(Wt[k][i] - ((k == gi) ? 1.0f : 0.0f), Vt2[k][j], acc);
      VB[gi * 256 + gj] = acc;
    }
    grid.sync();
    if (blk < 64) {  // upd: Vout = 2*Vin - Vin*T
      float (*Vr)[264] = (float(*)[264])&regionY[0];
      float (*Tt)[36]  = (float(*)[36])&regionY[32 * 264];
      const int rb = (blk >> 3) << 5, cb = (blk & 7) << 5;
      const int r32 = tid >> 5, cc8 = (tid & 31) << 3;
      *(float4*)&Vr[r32][cc8]     = *(const float4*)&Vin[(rb + r32) * 256 + cc8];
      *(float4*)&Vr[r32][cc8 + 4] = *(const float4*)&Vin[(rb + r32) * 256 + cc8 + 4];
      const int kr = tid >> 2, c8 = (tid & 3) << 3;
      *(float4*)&Tt[kr][c8]     = *(const float4*)&VB[kr * 256 + cb + c8];
      *(float4*)&Tt[kr][c8 + 4] = *(const float4*)&VB[kr * 256 + cb + c8 + 4];
      __syncthreads();
      const int i = tid >> 5, j = tid & 31;
      float acc = 0.f;
#pragma unroll 4
      for (int k = 0; k < 256; ++k)
        acc = fmaf(Vr[i][k], Tt[k][j], acc);
      Vout[(rb + i) * 256 + cb + j] = 2.0f * Vr[i][cb + j] - acc;
    }
    grid.sync();
  }

  // ==== u = V*b, c0 = b.u (block 0); blocks 16..31: VhB fragment-order =====
  if (blk == 0) {
    float* bs = &regionY[0];
    float* us = &regionY[256];
    if (tid < 256) bs[tid] = bvec[tid];
    __syncthreads();
    if (tid < 256) {
      float uacc = 0.f;
      for (int jj = 0; jj < 256; jj += 4) {
        const float4 v4 = *(const float4*)&VA[tid * 256 + jj];
        uacc += v4.x * bs[jj] + v4.y * bs[jj + 1] + v4.z * bs[jj + 2] + v4.w * bs[jj + 3];
      }
      ub[tid] = uacc;
      us[tid] = uacc * bs[tid];
    }
    __syncthreads();
    if (tid < 64) {
      float s = us[tid] + us[tid + 64] + us[tid + 128] + us[tid + 192];
#pragma unroll
      for (int off = 32; off > 0; off >>= 1) s += __shfl_down(s, off);
      if (tid == 0) c0g[0] = s;
    }
  } else if (blk >= 16 && blk < 32) {
    // VhB[((ct*8+kk)*64 + lane)*8 + e] = f16(V[ct*16 + (lane&15)][kk*32 + (lane>>4)*8 + e])
    // (V symmetric: B[k][c] = V[c][k]).  Each B-load = coalesced 1KB wave read.
    const int ct = blk - 16;
    const int kk = tid >> 7, rem = tid & 127;
    const int l = rem >> 1, e0 = (tid & 1) * 4;
    const float4 v4 = *(const float4*)&VA[(ct * 16 + (l & 15)) * 256 + kk * 32 + (l >> 4) * 8 + e0];
    __half* dst = VhB + ((size_t)(ct * 8 + kk) * 64 + l) * 8 + e0;
    *(__half2*)&dst[0] = __floats2half2_rn(v4.x, v4.y);
    *(__half2*)&dst[2] = __floats2half2_rn(v4.z, v4.w);
  }
  grid.sync();

  // =================== MFMA GEMM phase: Z = X*V, dots, out =================
  {
    const int g = tid & 31, l5 = tid >> 5, k0 = l5 << 3;  // unpack mapping
    const int w = tid >> 6, l = tid & 63;                 // wave / lane
    const int rt = w & 1, ctbase = (w >> 1) << 1;
    const int lm = l & 15, lh = l >> 4;
    if (tid < 256) ubuf[tid] = ub[tid];
    const float c0v = c0g[0];
    const __half* bp0 = VhB + (size_t)(ctbase * 8) * 512 + l * 8;        // ct0
    const __half* bp1 = VhB + (size_t)((ctbase + 1) * 8) * 512 + l * 8;  // ct1

#pragma unroll 1
    for (int t = 0; t < 9; ++t) {
      const bool active = (blk != 0) && ((t < 8) || has9);
      const int gb = (blk != 0) ? ((t < 8) ? ((blk - 1) * 8 + t) : (2040 + (blk & 7))) : 0;
      __syncthreads();   // previous batch fully consumed
      {  // unpack x_reg[t] -> xstage[sample][k] (one b128 store/thread)
        union { __half2 h2[4]; uint4 u4; } cv;
#pragma unroll
        for (int p = 0; p < 4; ++p) cv.h2[p] = x_reg[t][p];
        *(uint4*)&xstage[g][k0] = cv.u4;
      }
      if (tid < 128) ((float*)redbuf)[tid] = 0.f;
      __syncthreads();
      // ---- MFMA: 2 tiles/wave (16 samples x 16 cols each), K=256 ----
      f32x4 z0 = {0.f, 0.f, 0.f, 0.f}, z1 = {0.f, 0.f, 0.f, 0.f};
      const int srow = rt * 16 + lm;
#pragma unroll
      for (int kk = 0; kk < 8; ++kk) {
        const half8 a  = *(const half8*)&xstage[srow][kk * 32 + lh * 8];
        const half8 b0 = *(const half8*)&bp0[kk * 512];
        const half8 b1 = *(const half8*)&bp1[kk * 512];
        z0 = __builtin_amdgcn_mfma_f32_16x16x32_f16(a, b0, z0, 0, 0, 0);
        z1 = __builtin_amdgcn_mfma_f32_16x16x32_f16(a, b1, z1, 0, 0, 0);
      }
      // ---- epilogue: dp/dxx/dux over this wave's 32 cols ----
      float dp[4] = {}, dxx[4] = {}, dux[4] = {};
#pragma unroll
      for (int c = 0; c < 2; ++c) {
        const int col = (ctbase + c) * 16 + lm;
        const float uu = ubuf[col];
#pragma unroll
        for (int r = 0; r < 4; ++r) {
          const int s = rt * 16 + lh * 4 + r;
          const float xv = __half2float(xstage[s][col]);
          const float zz = (c == 0) ? z0[r] : z1[r];
          dp[r]  = fmaf(zz, xv, dp[r]);
          dxx[r] = fmaf(xv, xv, dxx[r]);
          dux[r] = fmaf(uu, xv, dux[r]);
        }
      }
#pragma unroll
      for (int off = 1; off < 16; off <<= 1)
#pragma unroll
        for (int r = 0; r < 4; ++r) {
          dp[r]  += __shfl_xor(dp[r], off);
          dxx[r] += __shfl_xor(dxx[r], off);
          dux[r] += __shfl_xor(dux[r], off);
        }
      if (lm == 0) {
#pragma unroll
        for (int r = 0; r < 4; ++r) {
          atomicAdd(&redbuf[rt][lh * 4 + r][0], dp[r]);
          atomicAdd(&redbuf[rt][lh * 4 + r][1], dxx[r]);
          atomicAdd(&redbuf[rt][lh * 4 + r][2], dux[r]);
        }
      }
      __syncthreads();
      if (active && tid < 32) {
        const int rr = tid >> 4, si = tid & 15;
        const float* rv = redbuf[rr][si];
        out[gb * 32 + rr * 16 + si] = 3.0f * rv[0] - rv[2] - 0.25f * c0v - rv[1];
      }
    }
  }
}

// ============================ launcher ======================================
extern "C" void kernel_launch(void* const* d_in, const int* in_sizes, int n_in,
                              void* d_out, int out_size, void* d_ws, size_t ws_size,
                              hipStream_t stream) {
  const float* E_ent   = (const float*)d_in[0];
  const float* E_rel   = (const float*)d_in[1];
  const float* W       = (const float*)d_in[2];
  const float* bvec    = (const float*)d_in[3];
  const int*   samples = (const int*)d_in[4];
  float* out = (float*)d_out;
  float* ws  = (float*)d_ws;

  float* VA = ws;                      // 65536 f32 (final V)
  float* VB = ws + 65536;              // NS scratch T
  float* VC = ws + 131072;             // NS intermediate
  float* ub = ws + 196608;             // 256
  float* c0 = ws + 196864;             // 1 (+pad)
  __half* VhB = (__half*)(ws + 197120);// 131072 f16 = 256 KB (fragment order)

  void* args[] = {(void*)&E_ent, (void*)&E_rel, (void*)&W, (void*)&bvec,
                  (void*)&samples, (void*)&out, (void*)&VA, (void*)&VB,
                  (void*)&VC, (void*)&ub, (void*)&c0, (void*)&VhB};
  hipLaunchCooperativeKernel((void*)fused_kernel, dim3(256), dim3(1024),
                             args, 0, stream);
}

// Round 8
// 1019.749 us; speedup vs baseline: 1.0556x; 1.0075x over previous
//
#include <hip/hip_runtime.h>
#include <hip/hip_fp16.h>
#include <hip/hip_cooperative_groups.h>

namespace cg = cooperative_groups;

typedef _Float16 half8 __attribute__((ext_vector_type(8)));
typedef float f32x4 __attribute__((ext_vector_type(4)));

// ---------------------------------------------------------------------------
// DistMultNN fused cooperative kernel (MI355X).
// out[s] = 3*x^T V x - (Vb).x - 0.25*(b^T V b) - x.x,  x = r * circcorr(e1,e2)
// 256 blocks x 1024 threads cooperative:
//   phase1: block 0 = blocked Gauss-Jordan inverse; blocks 1..255 = cc+x
//   -> NS polish x2 -> u,c0; blocks 16..31 build VhB = f16(V) in MFMA
//      fragment order (coalesced 1KB B-loads; V symmetric)
//   -> per-batch MFMA GEMM, batch loop FULLY UNROLLED so x_reg indices are
//      compile-time (rule #20: dynamic index demotes to scratch) -> out.
// ---------------------------------------------------------------------------

#define ERS 268      // e1/e2 LDS row stride (floats)
#define XSS 280      // xstage row stride (halfs)
#define REGION_F 18432

__global__ __launch_bounds__(1024, 4)
void fused_kernel(const float* __restrict__ E_ent, const float* __restrict__ E_rel,
                  const float* __restrict__ W, const float* __restrict__ bvec,
                  const int* __restrict__ samples, float* __restrict__ out,
                  float* __restrict__ VA, float* __restrict__ VB, float* __restrict__ VC,
                  float* __restrict__ ub, float* __restrict__ c0g,
                  __half* __restrict__ VhB) {
  __shared__ float regionY[REGION_F];     // 73.7 KB, phase-unioned
  __shared__ __half xstage[32][XSS];      // 17.5 KB: x[sample][k] per batch
  __shared__ float ubuf[256];
  __shared__ float redbuf[2][16][4];      // per-batch (dp, dxx, dux) accum

  const int tid = threadIdx.x;
  const int blk = blockIdx.x;
  cg::grid_group grid = cg::this_grid();

  __half2 x_reg[9][4];                    // packed x, 9 batches x 8 k-values
#pragma unroll
  for (int t = 0; t < 9; ++t)
#pragma unroll
    for (int p = 0; p < 4; ++p) x_reg[t][p] = __floats2half2_rn(0.f, 0.f);

  const bool has9 = (blk >= 248);

  // =================== phase 1: GJ (block 0) || cc (blocks 1..255) =========
  if (blk == 0) {
    // ---- blocked in-place Gauss-Jordan (round-3 code; b64 colbuf reads) ----
    const int tx = tid & 31, ty = tid >> 5;
    const int r0 = ty << 3, gc0 = tx << 3;
    float (*rowbuf)[264] = (float(*)[264])&regionY[0];        // 8 x 264
    float (*colbuf)[8]   = (float(*)[8])&regionY[8 * 264];    // 256 x 8
    float gg[8][8];
#pragma unroll
    for (int i = 0; i < 8; ++i) {
      const float4 wa = *(const float4*)&W[(r0 + i) * 256 + gc0];
      const float4 wb = *(const float4*)&W[(r0 + i) * 256 + gc0 + 4];
      gg[i][0] = wa.x; gg[i][1] = wa.y; gg[i][2] = wa.z; gg[i][3] = wa.w;
      gg[i][4] = wb.x; gg[i][5] = wb.y; gg[i][6] = wb.z; gg[i][7] = wb.w;
#pragma unroll
      for (int j = 0; j < 8; ++j)
        if ((r0 + i) == (gc0 + j)) gg[i][j] -= 1.0f;
    }
    __syncthreads();
    for (int kg = 0; kg < 32; ++kg) {
      if (ty == kg) {
        const int L0 = (kg & 1) << 5;
#pragma unroll
        for (int kj = 0; kj < 8; ++kj) {
          float c[8];
#pragma unroll
          for (int i = 0; i < 8; ++i) c[i] = __shfl(gg[i][kj], L0 + kg, 64);
          const float pr = 1.0f / c[kj];
#pragma unroll
          for (int j = 0; j < 8; ++j) gg[kj][j] *= pr;
          if (tx == kg) gg[kj][kj] = pr;
#pragma unroll
          for (int i = 0; i < 8; ++i) {
            if (i == kj) continue;
#pragma unroll
            for (int j = 0; j < 8; ++j) gg[i][j] = fmaf(-c[i], gg[kj][j], gg[i][j]);
            if (tx == kg) gg[i][kj] = -c[i] * pr;
          }
        }
#pragma unroll
        for (int m = 0; m < 8; ++m) {
          float r4[8];
#pragma unroll
          for (int j = 0; j < 8; ++j)
            r4[j] = gg[m][j] + ((tx == kg && j == m) ? 1.0f : 0.0f);
          *(float4*)&rowbuf[m][gc0]     = make_float4(r4[0], r4[1], r4[2], r4[3]);
          *(float4*)&rowbuf[m][gc0 + 4] = make_float4(r4[4], r4[5], r4[6], r4[7]);
        }
      } else if (tx == kg) {
#pragma unroll
        for (int i = 0; i < 8; ++i) {
          *(float4*)&colbuf[r0 + i][0] = make_float4(gg[i][0], gg[i][1], gg[i][2], gg[i][3]);
          *(float4*)&colbuf[r0 + i][4] = make_float4(gg[i][4], gg[i][5], gg[i][6], gg[i][7]);
        }
      }
      __syncthreads();
      if (ty != kg) {
#pragma unroll
        for (int mp = 0; mp < 4; ++mp) {
          float ra[8], rb[8];
          {
            const float4 t0 = *(const float4*)&rowbuf[2 * mp][gc0];
            const float4 t1 = *(const float4*)&rowbuf[2 * mp][gc0 + 4];
            ra[0] = t0.x; ra[1] = t0.y; ra[2] = t0.z; ra[3] = t0.w;
            ra[4] = t1.x; ra[5] = t1.y; ra[6] = t1.z; ra[7] = t1.w;
            const float4 t2 = *(const float4*)&rowbuf[2 * mp + 1][gc0];
            const float4 t3 = *(const float4*)&rowbuf[2 * mp + 1][gc0 + 4];
            rb[0] = t2.x; rb[1] = t2.y; rb[2] = t2.z; rb[3] = t2.w;
            rb[4] = t3.x; rb[5] = t3.y; rb[6] = t3.z; rb[7] = t3.w;
          }
#pragma unroll
          for (int i = 0; i < 8; ++i) {
            const float2 fi = *(const float2*)&colbuf[r0 + i][2 * mp];
#pragma unroll
            for (int j = 0; j < 8; ++j) {
              gg[i][j] = fmaf(-fi.x, ra[j], gg[i][j]);
              gg[i][j] = fmaf(-fi.y, rb[j], gg[i][j]);
            }
          }
        }
      }
      __syncthreads();
    }
#pragma unroll
    for (int i = 0; i < 8; ++i) {
      *(float4*)&VA[(r0 + i) * 256 + gc0]     = make_float4(gg[i][0], gg[i][1], gg[i][2], gg[i][3]);
      *(float4*)&VA[(r0 + i) * 256 + gc0 + 4] = make_float4(gg[i][4], gg[i][5], gg[i][6], gg[i][7]);
    }
  } else {
    // ---- cc + x for up to 9 batches of 32 samples, pack f16 into regs ----
    float (*e1buf)[ERS] = (float(*)[ERS])&regionY[0];
    float (*e2buf)[ERS] = (float(*)[ERS])&regionY[32 * ERS];
    const int g = tid & 31, l5 = tid >> 5, k0 = l5 << 3;
    const int ss = tid >> 5, f0 = (tid & 31) << 3;
#pragma unroll
    for (int t = 0; t < 9; ++t) {
      const int gb = (t < 8) ? ((blk - 1) * 8 + t) : (2040 + (blk & 7));
      const int sb = gb << 5;
      __syncthreads();
      {
        const int ie1 = samples[(sb + ss) * 3 + 0];
        const int ie2 = samples[(sb + ss) * 3 + 2];
        const float* p1 = E_ent + (size_t)ie1 * 256 + f0;
        const float* p2 = E_ent + (size_t)ie2 * 256 + f0;
        *(float4*)&e1buf[ss][f0]     = *(const float4*)&p1[0];
        *(float4*)&e1buf[ss][f0 + 4] = *(const float4*)&p1[4];
        *(float4*)&e2buf[ss][f0]     = *(const float4*)&p2[0];
        *(float4*)&e2buf[ss][f0 + 4] = *(const float4*)&p2[4];
      }
      __syncthreads();
      float acc[8] = {};
#pragma unroll 2
      for (int j0 = 0; j0 < 256; j0 += 8) {
        float e1v[8], ew[16];
        {
          const float4 a = *(const float4*)&e1buf[g][j0];
          const float4 b = *(const float4*)&e1buf[g][j0 + 4];
          e1v[0] = a.x; e1v[1] = a.y; e1v[2] = a.z; e1v[3] = a.w;
          e1v[4] = b.x; e1v[5] = b.y; e1v[6] = b.z; e1v[7] = b.w;
        }
        const int h0 = (j0 + k0) & 255;
        const int h1 = (h0 + 8) & 255;
        {
          const float4 a = *(const float4*)&e2buf[g][h0];
          const float4 b = *(const float4*)&e2buf[g][h0 + 4];
          const float4 c = *(const float4*)&e2buf[g][h1];
          const float4 d = *(const float4*)&e2buf[g][h1 + 4];
          ew[0] = a.x;  ew[1] = a.y;  ew[2] = a.z;  ew[3] = a.w;
          ew[4] = b.x;  ew[5] = b.y;  ew[6] = b.z;  ew[7] = b.w;
          ew[8] = c.x;  ew[9] = c.y;  ew[10] = c.z; ew[11] = c.w;
          ew[12] = d.x; ew[13] = d.y; ew[14] = d.z; ew[15] = d.w;
        }
#pragma unroll
        for (int m = 0; m < 8; ++m)
#pragma unroll
          for (int jj = 0; jj < 8; ++jj)
            acc[m] = fmaf(e1v[jj], ew[jj + m], acc[m]);
      }
      const int ir = samples[(sb + g) * 3 + 1];
      const float* rp = E_rel + (size_t)ir * 256 + k0;
      const float4 r0v = *(const float4*)&rp[0];
      const float4 r1v = *(const float4*)&rp[4];
      x_reg[t][0] = __floats2half2_rn(r0v.x * acc[0], r0v.y * acc[1]);
      x_reg[t][1] = __floats2half2_rn(r0v.z * acc[2], r0v.w * acc[3]);
      x_reg[t][2] = __floats2half2_rn(r1v.x * acc[4], r1v.y * acc[5]);
      x_reg[t][3] = __floats2half2_rn(r1v.z * acc[6], r1v.w * acc[7]);
    }
  }
  grid.sync();

  // =================== Newton-Schulz polish x2 (blocks 0..63) ==============
#pragma unroll 1
  for (int it = 0; it < 2; ++it) {
    const float* Vin = (it == 0) ? VA : VC;
    float* Vout      = (it == 0) ? VC : VA;
    if (blk < 64) {  // mt: T = (W-I)*Vin
      float (*Wt)[36]  = (float(*)[36])&regionY[0];
      float (*Vt2)[36] = (float(*)[36])&regionY[9216];
      const int cbW = (blk >> 3) << 5, cbV = (blk & 7) << 5;
      const int kr = tid >> 2, c8 = (tid & 3) << 3;
      *(float4*)&Wt[kr][c8]      = *(const float4*)&W[kr * 256 + cbW + c8];
      *(float4*)&Wt[kr][c8 + 4]  = *(const float4*)&W[kr * 256 + cbW + c8 + 4];
      *(float4*)&Vt2[kr][c8]     = *(const float4*)&Vin[kr * 256 + cbV + c8];
      *(float4*)&Vt2[kr][c8 + 4] = *(const float4*)&Vin[kr * 256 + cbV + c8 + 4];
      __syncthreads();
      const int i = tid >> 5, j = tid & 31;
      const int gi = cbW + i, gj = cbV + j;
      float acc = 0.f;
#pragma unroll 4
      for (int k = 0; k < 256; ++k)
        acc = fmaf(Wt[k][i] - ((k == gi) ? 1.0f : 0.0f), Vt2[k][j], acc);
      VB[gi * 256 + gj] = acc;
    }
    grid.sync();
    if (blk < 64) {  // upd: Vout = 2*Vin - Vin*T
      float (*Vr)[264] = (float(*)[264])&regionY[0];
      float (*Tt)[36]  = (float(*)[36])&regionY[32 * 264];
      const int rb = (blk >> 3) << 5, cb = (blk & 7) << 5;
      const int r32 = tid >> 5, cc8 = (tid & 31) << 3;
      *(float4*)&Vr[r32][cc8]     = *(const float4*)&Vin[(rb + r32) * 256 + cc8];
      *(float4*)&Vr[r32][cc8 + 4] = *(const float4*)&Vin[(rb + r32) * 256 + cc8 + 4];
      const int kr = tid >> 2, c8 = (tid & 3) << 3;
      *(float4*)&Tt[kr][c8]     = *(const float4*)&VB[kr * 256 + cb + c8];
      *(float4*)&Tt[kr][c8 + 4] = *(const float4*)&VB[kr * 256 + cb + c8 + 4];
      __syncthreads();
      const int i = tid >> 5, j = tid & 31;
      float acc = 0.f;
#pragma unroll 4
      for (int k = 0; k < 256; ++k)
        acc = fmaf(Vr[i][k], Tt[k][j], acc);
      Vout[(rb + i) * 256 + cb + j] = 2.0f * Vr[i][cb + j] - acc;
    }
    grid.sync();
  }

  // ==== u = V*b, c0 = b.u (block 0); blocks 16..31: VhB fragment-order =====
  if (blk == 0) {
    float* bs = &regionY[0];
    float* us = &regionY[256];
    if (tid < 256) bs[tid] = bvec[tid];
    __syncthreads();
    if (tid < 256) {
      float uacc = 0.f;
      for (int jj = 0; jj < 256; jj += 4) {
        const float4 v4 = *(const float4*)&VA[tid * 256 + jj];
        uacc += v4.x * bs[jj] + v4.y * bs[jj + 1] + v4.z * bs[jj + 2] + v4.w * bs[jj + 3];
      }
      ub[tid] = uacc;
      us[tid] = uacc * bs[tid];
    }
    __syncthreads();
    if (tid < 64) {
      float s = us[tid] + us[tid + 64] + us[tid + 128] + us[tid + 192];
#pragma unroll
      for (int off = 32; off > 0; off >>= 1) s += __shfl_down(s, off);
      if (tid == 0) c0g[0] = s;
    }
  } else if (blk >= 16 && blk < 32) {
    // VhB[((ct*8+kk)*64 + lane)*8 + e] = f16(V[ct*16 + (lane&15)][kk*32 + (lane>>4)*8 + e])
    // (V symmetric: B[k][c] = V[c][k]).  Each B-load = coalesced 1KB wave read.
    const int ct = blk - 16;
    const int kk = tid >> 7, rem = tid & 127;
    const int l = rem >> 1, e0 = (tid & 1) * 4;
    const float4 v4 = *(const float4*)&VA[(ct * 16 + (l & 15)) * 256 + kk * 32 + (l >> 4) * 8 + e0];
    __half* dst = VhB + ((size_t)(ct * 8 + kk) * 64 + l) * 8 + e0;
    *(__half2*)&dst[0] = __floats2half2_rn(v4.x, v4.y);
    *(__half2*)&dst[2] = __floats2half2_rn(v4.z, v4.w);
  }
  grid.sync();

  // ====== MFMA GEMM phase: Z = X*V, dots, out (batch loop FULLY UNROLLED) ==
  {
    const int g = tid & 31, l5 = tid >> 5, k0 = l5 << 3;  // unpack mapping
    const int w = tid >> 6, l = tid & 63;                 // wave / lane
    const int rt = w & 1, ctbase = (w >> 1) << 1;
    const int lm = l & 15, lh = l >> 4;
    if (tid < 256) ubuf[tid] = ub[tid];
    const float c0v = c0g[0];
    const __half* bp0 = VhB + (size_t)(ctbase * 8) * 512 + l * 8;        // ct0
    const __half* bp1 = VhB + (size_t)((ctbase + 1) * 8) * 512 + l * 8;  // ct1
    const int srow = rt * 16 + lm;

#pragma unroll
    for (int t = 0; t < 9; ++t) {           // STATIC t: x_reg stays in regs
      const bool active = (blk != 0) && ((t < 8) || has9);
      const int gb = (blk != 0) ? ((t < 8) ? ((blk - 1) * 8 + t) : (2040 + (blk & 7))) : 0;
      __syncthreads();   // previous batch fully consumed
      {  // unpack x_reg[t] -> xstage[sample][k] (one b128 store/thread)
        union { __half2 h2[4]; uint4 u4; } cv;
        cv.h2[0] = x_reg[t][0]; cv.h2[1] = x_reg[t][1];
        cv.h2[2] = x_reg[t][2]; cv.h2[3] = x_reg[t][3];
        *(uint4*)&xstage[g][k0] = cv.u4;
      }
      if (tid < 128) ((float*)redbuf)[tid] = 0.f;
      __syncthreads();
      // ---- MFMA: 2 tiles/wave (16 samples x 16 cols each), K=256 ----
      f32x4 z0 = {0.f, 0.f, 0.f, 0.f}, z1 = {0.f, 0.f, 0.f, 0.f};
#pragma unroll
      for (int kk = 0; kk < 8; ++kk) {
        const half8 a  = *(const half8*)&xstage[srow][kk * 32 + lh * 8];
        const half8 b0 = *(const half8*)&bp0[kk * 512];
        const half8 b1 = *(const half8*)&bp1[kk * 512];
        z0 = __builtin_amdgcn_mfma_f32_16x16x32_f16(a, b0, z0, 0, 0, 0);
        z1 = __builtin_amdgcn_mfma_f32_16x16x32_f16(a, b1, z1, 0, 0, 0);
      }
      // ---- epilogue: dp/dxx/dux over this wave's 32 cols ----
      float dp[4] = {}, dxx[4] = {}, dux[4] = {};
#pragma unroll
      for (int c = 0; c < 2; ++c) {
        const int col = (ctbase + c) * 16 + lm;
        const float uu = ubuf[col];
#pragma unroll
        for (int r = 0; r < 4; ++r) {
          const int s = rt * 16 + lh * 4 + r;
          const float xv = __half2float(xstage[s][col]);
          const float zz = (c == 0) ? z0[r] : z1[r];
          dp[r]  = fmaf(zz, xv, dp[r]);
          dxx[r] = fmaf(xv, xv, dxx[r]);
          dux[r] = fmaf(uu, xv, dux[r]);
        }
      }
#pragma unroll
      for (int off = 1; off < 16; off <<= 1)
#pragma unroll
        for (int r = 0; r < 4; ++r) {
          dp[r]  += __shfl_xor(dp[r], off);
          dxx[r] += __shfl_xor(dxx[r], off);
          dux[r] += __shfl_xor(dux[r], off);
        }
      if (lm == 0) {
#pragma unroll
        for (int r = 0; r < 4; ++r) {
          atomicAdd(&redbuf[rt][lh * 4 + r][0], dp[r]);
          atomicAdd(&redbuf[rt][lh * 4 + r][1], dxx[r]);
          atomicAdd(&redbuf[rt][lh * 4 + r][2], dux[r]);
        }
      }
      __syncthreads();
      if (active && tid < 32) {
        const int rr = tid >> 4, si = tid & 15;
        const float* rv = redbuf[rr][si];
        out[gb * 32 + rr * 16 + si] = 3.0f * rv[0] - rv[2] - 0.25f * c0v - rv[1];
      }
    }
  }
}

// ============================ launcher ======================================
extern "C" void kernel_launch(void* const* d_in, const int* in_sizes, int n_in,
                              void* d_out, int out_size, void* d_ws, size_t ws_size,
                              hipStream_t stream) {
  const float* E_ent   = (const float*)d_in[0];
  const float* E_rel   = (const float*)d_in[1];
  const float* W       = (const float*)d_in[2];
  const float* bvec    = (const float*)d_in[3];
  const int*   samples = (const int*)d_in[4];
  float* out = (float*)d_out;
  float* ws  = (float*)d_ws;

  float* VA = ws;                      // 65536 f32 (final V)
  float* VB = ws + 65536;              // NS scratch T
  float* VC = ws + 131072;             // NS intermediate
  float* ub = ws + 196608;             // 256
  float* c0 = ws + 196864;             // 1 (+pad)
  __half* VhB = (__half*)(ws + 197120);// 131072 f16 = 256 KB (fragment order)

  void* args[] = {(void*)&E_ent, (void*)&E_rel, (void*)&W, (void*)&bvec,
                  (void*)&samples, (void*)&out, (void*)&VA, (void*)&VB,
                  (void*)&VC, (void*)&ub, (void*)&c0, (void*)&VhB};
  hipLaunchCooperativeKernel((void*)fused_kernel, dim3(256), dim3(1024),
                             args, 0, stream);
}

// Round 9
// 987.565 us; speedup vs baseline: 1.0900x; 1.0326x over previous
//
#include <hip/hip_runtime.h>
#include <hip/hip_fp16.h>
#include <hip/hip_cooperative_groups.h>

namespace cg = cooperative_groups;

typedef _Float16 half8 __attribute__((ext_vector_type(8)));
typedef float f32x4 __attribute__((ext_vector_type(4)));

// ---------------------------------------------------------------------------
// DistMultNN fused cooperative kernel (MI355X).
// out[s] = 3*x^T V x - (Vb).x - 0.25*(b^T V b) - x.x,  x = r * circcorr(e1,e2)
// 256 blocks x 1024 threads cooperative:
//   phase1: block 0 = blocked Gauss-Jordan inverse; blocks 1..255 = cc+x,
//           x stored to GLOBAL XgA in MFMA A-fragment order (NO cross-phase
//           register state -> no scratch spills; coalesced 1KB wave loads).
//   -> NS polish x2 -> u,c0; blocks 16..31 build VhB = f16(V) fragment order
//   -> per-batch MFMA GEMM (A: XgA global->regs, B: VhB global) + epilogue.
// ---------------------------------------------------------------------------

#define ERS 268      // e1/e2 LDS row stride (floats)
#define XSS 280      // xstage row stride (halfs)
#define REGION_F 18432

__global__ __launch_bounds__(1024, 4)
void fused_kernel(const float* __restrict__ E_ent, const float* __restrict__ E_rel,
                  const float* __restrict__ W, const float* __restrict__ bvec,
                  const int* __restrict__ samples, float* __restrict__ out,
                  float* __restrict__ VA, float* __restrict__ VB, float* __restrict__ VC,
                  float* __restrict__ ub, float* __restrict__ c0g,
                  __half* __restrict__ VhB, __half* __restrict__ XgA) {
  __shared__ float regionY[REGION_F];     // 73.7 KB, phase-unioned
  __shared__ __half xstage[32][XSS];      // 17.5 KB: x[sample][k] per batch
  __shared__ float ubuf[256];
  __shared__ float redbuf[2][16][4];      // per-batch (dp, dxx, dux) accum

  const int tid = threadIdx.x;
  const int blk = blockIdx.x;
  cg::grid_group grid = cg::this_grid();

  const bool has9 = (blk >= 248);

  // =================== phase 1: GJ (block 0) || cc (blocks 1..255) =========
  if (blk == 0) {
    // ---- blocked in-place Gauss-Jordan (round-3 code; b64 colbuf reads) ----
    const int tx = tid & 31, ty = tid >> 5;
    const int r0 = ty << 3, gc0 = tx << 3;
    float (*rowbuf)[264] = (float(*)[264])&regionY[0];        // 8 x 264
    float (*colbuf)[8]   = (float(*)[8])&regionY[8 * 264];    // 256 x 8
    float gg[8][8];
#pragma unroll
    for (int i = 0; i < 8; ++i) {
      const float4 wa = *(const float4*)&W[(r0 + i) * 256 + gc0];
      const float4 wb = *(const float4*)&W[(r0 + i) * 256 + gc0 + 4];
      gg[i][0] = wa.x; gg[i][1] = wa.y; gg[i][2] = wa.z; gg[i][3] = wa.w;
      gg[i][4] = wb.x; gg[i][5] = wb.y; gg[i][6] = wb.z; gg[i][7] = wb.w;
#pragma unroll
      for (int j = 0; j < 8; ++j)
        if ((r0 + i) == (gc0 + j)) gg[i][j] -= 1.0f;
    }
    __syncthreads();
    for (int kg = 0; kg < 32; ++kg) {
      if (ty == kg) {
        const int L0 = (kg & 1) << 5;
#pragma unroll
        for (int kj = 0; kj < 8; ++kj) {
          float c[8];
#pragma unroll
          for (int i = 0; i < 8; ++i) c[i] = __shfl(gg[i][kj], L0 + kg, 64);
          const float pr = 1.0f / c[kj];
#pragma unroll
          for (int j = 0; j < 8; ++j) gg[kj][j] *= pr;
          if (tx == kg) gg[kj][kj] = pr;
#pragma unroll
          for (int i = 0; i < 8; ++i) {
            if (i == kj) continue;
#pragma unroll
            for (int j = 0; j < 8; ++j) gg[i][j] = fmaf(-c[i], gg[kj][j], gg[i][j]);
            if (tx == kg) gg[i][kj] = -c[i] * pr;
          }
        }
#pragma unroll
        for (int m = 0; m < 8; ++m) {
          float r4[8];
#pragma unroll
          for (int j = 0; j < 8; ++j)
            r4[j] = gg[m][j] + ((tx == kg && j == m) ? 1.0f : 0.0f);
          *(float4*)&rowbuf[m][gc0]     = make_float4(r4[0], r4[1], r4[2], r4[3]);
          *(float4*)&rowbuf[m][gc0 + 4] = make_float4(r4[4], r4[5], r4[6], r4[7]);
        }
      } else if (tx == kg) {
#pragma unroll
        for (int i = 0; i < 8; ++i) {
          *(float4*)&colbuf[r0 + i][0] = make_float4(gg[i][0], gg[i][1], gg[i][2], gg[i][3]);
          *(float4*)&colbuf[r0 + i][4] = make_float4(gg[i][4], gg[i][5], gg[i][6], gg[i][7]);
        }
      }
      __syncthreads();
      if (ty != kg) {
#pragma unroll
        for (int mp = 0; mp < 4; ++mp) {
          float ra[8], rb[8];
          {
            const float4 t0 = *(const float4*)&rowbuf[2 * mp][gc0];
            const float4 t1 = *(const float4*)&rowbuf[2 * mp][gc0 + 4];
            ra[0] = t0.x; ra[1] = t0.y; ra[2] = t0.z; ra[3] = t0.w;
            ra[4] = t1.x; ra[5] = t1.y; ra[6] = t1.z; ra[7] = t1.w;
            const float4 t2 = *(const float4*)&rowbuf[2 * mp + 1][gc0];
            const float4 t3 = *(const float4*)&rowbuf[2 * mp + 1][gc0 + 4];
            rb[0] = t2.x; rb[1] = t2.y; rb[2] = t2.z; rb[3] = t2.w;
            rb[4] = t3.x; rb[5] = t3.y; rb[6] = t3.z; rb[7] = t3.w;
          }
#pragma unroll
          for (int i = 0; i < 8; ++i) {
            const float2 fi = *(const float2*)&colbuf[r0 + i][2 * mp];
#pragma unroll
            for (int j = 0; j < 8; ++j) {
              gg[i][j] = fmaf(-fi.x, ra[j], gg[i][j]);
              gg[i][j] = fmaf(-fi.y, rb[j], gg[i][j]);
            }
          }
        }
      }
      __syncthreads();
    }
#pragma unroll
    for (int i = 0; i < 8; ++i) {
      *(float4*)&VA[(r0 + i) * 256 + gc0]     = make_float4(gg[i][0], gg[i][1], gg[i][2], gg[i][3]);
      *(float4*)&VA[(r0 + i) * 256 + gc0 + 4] = make_float4(gg[i][4], gg[i][5], gg[i][6], gg[i][7]);
    }
  } else {
    // ---- cc + x for up to 9 batches of 32 samples; x -> XgA (frag order) ---
    float (*e1buf)[ERS] = (float(*)[ERS])&regionY[0];
    float (*e2buf)[ERS] = (float(*)[ERS])&regionY[32 * ERS];
    const int g = tid & 31, l5 = tid >> 5, k0 = l5 << 3;
    const int ss = tid >> 5, f0 = (tid & 31) << 3;
    // fragment coords for this thread's 8 k-values of sample g:
    const int kkf = l5 >> 2, lhf = l5 & 3;
    const int rtf = g >> 4, lanef = (lhf << 4) | (g & 15);
#pragma unroll 1
    for (int t = 0; t < 9; ++t) {
      if (t == 8 && !has9) break;
      const int gb = (t < 8) ? ((blk - 1) * 8 + t) : (2040 + (blk & 7));
      const int sb = gb << 5;
      __syncthreads();
      {
        const int ie1 = samples[(sb + ss) * 3 + 0];
        const int ie2 = samples[(sb + ss) * 3 + 2];
        const float* p1 = E_ent + (size_t)ie1 * 256 + f0;
        const float* p2 = E_ent + (size_t)ie2 * 256 + f0;
        *(float4*)&e1buf[ss][f0]     = *(const float4*)&p1[0];
        *(float4*)&e1buf[ss][f0 + 4] = *(const float4*)&p1[4];
        *(float4*)&e2buf[ss][f0]     = *(const float4*)&p2[0];
        *(float4*)&e2buf[ss][f0 + 4] = *(const float4*)&p2[4];
      }
      __syncthreads();
      float acc[8] = {};
#pragma unroll 2
      for (int j0 = 0; j0 < 256; j0 += 8) {
        float e1v[8], ew[16];
        {
          const float4 a = *(const float4*)&e1buf[g][j0];
          const float4 b = *(const float4*)&e1buf[g][j0 + 4];
          e1v[0] = a.x; e1v[1] = a.y; e1v[2] = a.z; e1v[3] = a.w;
          e1v[4] = b.x; e1v[5] = b.y; e1v[6] = b.z; e1v[7] = b.w;
        }
        const int h0 = (j0 + k0) & 255;
        const int h1 = (h0 + 8) & 255;
        {
          const float4 a = *(const float4*)&e2buf[g][h0];
          const float4 b = *(const float4*)&e2buf[g][h0 + 4];
          const float4 c = *(const float4*)&e2buf[g][h1];
          const float4 d = *(const float4*)&e2buf[g][h1 + 4];
          ew[0] = a.x;  ew[1] = a.y;  ew[2] = a.z;  ew[3] = a.w;
          ew[4] = b.x;  ew[5] = b.y;  ew[6] = b.z;  ew[7] = b.w;
          ew[8] = c.x;  ew[9] = c.y;  ew[10] = c.z; ew[11] = c.w;
          ew[12] = d.x; ew[13] = d.y; ew[14] = d.z; ew[15] = d.w;
        }
#pragma unroll
        for (int m = 0; m < 8; ++m)
#pragma unroll
          for (int jj = 0; jj < 8; ++jj)
            acc[m] = fmaf(e1v[jj], ew[jj + m], acc[m]);
      }
      const int ir = samples[(sb + g) * 3 + 1];
      const float* rp = E_rel + (size_t)ir * 256 + k0;
      const float4 r0v = *(const float4*)&rp[0];
      const float4 r1v = *(const float4*)&rp[4];
      union { __half2 h2[4]; uint4 u4; } cv;
      cv.h2[0] = __floats2half2_rn(r0v.x * acc[0], r0v.y * acc[1]);
      cv.h2[1] = __floats2half2_rn(r0v.z * acc[2], r0v.w * acc[3]);
      cv.h2[2] = __floats2half2_rn(r1v.x * acc[4], r1v.y * acc[5]);
      cv.h2[3] = __floats2half2_rn(r1v.z * acc[6], r1v.w * acc[7]);
      // XgA[((gb*2 + rt)*8 + kk)*64 + lane][0..7] : A-fragment order
      *(uint4*)&XgA[((size_t)((gb * 2 + rtf) * 8 + kkf) * 64 + lanef) * 8] = cv.u4;
    }
  }
  grid.sync();

  // =================== Newton-Schulz polish x2 (blocks 0..63) ==============
#pragma unroll 1
  for (int it = 0; it < 2; ++it) {
    const float* Vin = (it == 0) ? VA : VC;
    float* Vout      = (it == 0) ? VC : VA;
    if (blk < 64) {  // mt: T = (W-I)*Vin
      float (*Wt)[36]  = (float(*)[36])&regionY[0];
      float (*Vt2)[36] = (float(*)[36])&regionY[9216];
      const int cbW = (blk >> 3) << 5, cbV = (blk & 7) << 5;
      const int kr = tid >> 2, c8 = (tid & 3) << 3;
      *(float4*)&Wt[kr][c8]      = *(const float4*)&W[kr * 256 + cbW + c8];
      *(float4*)&Wt[kr][c8 + 4]  = *(const float4*)&W[kr * 256 + cbW + c8 + 4];
      *(float4*)&Vt2[kr][c8]     = *(const float4*)&Vin[kr * 256 + cbV + c8];
      *(float4*)&Vt2[kr][c8 + 4] = *(const float4*)&Vin[kr * 256 + cbV + c8 + 4];
      __syncthreads();
      const int i = tid >> 5, j = tid & 31;
      const int gi = cbW + i, gj = cbV + j;
      float acc = 0.f;
#pragma unroll 4
      for (int k = 0; k < 256; ++k)
        acc = fmaf(Wt[k][i] - ((k == gi) ? 1.0f : 0.0f), Vt2[k][j], acc);
      VB[gi * 256 + gj] = acc;
    }
    grid.sync();
    if (blk < 64) {  // upd: Vout = 2*Vin - Vin*T
      float (*Vr)[264] = (float(*)[264])&regionY[0];
      float (*Tt)[36]  = (float(*)[36])&regionY[32 * 264];
      const int rb = (blk >> 3) << 5, cb = (blk & 7) << 5;
      const int r32 = tid >> 5, cc8 = (tid & 31) << 3;
      *(float4*)&Vr[r32][cc8]     = *(const float4*)&Vin[(rb + r32) * 256 + cc8];
      *(float4*)&Vr[r32][cc8 + 4] = *(const float4*)&Vin[(rb + r32) * 256 + cc8 + 4];
      const int kr = tid >> 2, c8 = (tid & 3) << 3;
      *(float4*)&Tt[kr][c8]     = *(const float4*)&VB[kr * 256 + cb + c8];
      *(float4*)&Tt[kr][c8 + 4] = *(const float4*)&VB[kr * 256 + cb + c8 + 4];
      __syncthreads();
      const int i = tid >> 5, j = tid & 31;
      float acc = 0.f;
#pragma unroll 4
      for (int k = 0; k < 256; ++k)
        acc = fmaf(Vr[i][k], Tt[k][j], acc);
      Vout[(rb + i) * 256 + cb + j] = 2.0f * Vr[i][cb + j] - acc;
    }
    grid.sync();
  }

  // ==== u = V*b, c0 = b.u (block 0); blocks 16..31: VhB fragment-order =====
  if (blk == 0) {
    float* bs = &regionY[0];
    float* us = &regionY[256];
    if (tid < 256) bs[tid] = bvec[tid];
    __syncthreads();
    if (tid < 256) {
      float uacc = 0.f;
      for (int jj = 0; jj < 256; jj += 4) {
        const float4 v4 = *(const float4*)&VA[tid * 256 + jj];
        uacc += v4.x * bs[jj] + v4.y * bs[jj + 1] + v4.z * bs[jj + 2] + v4.w * bs[jj + 3];
      }
      ub[tid] = uacc;
      us[tid] = uacc * bs[tid];
    }
    __syncthreads();
    if (tid < 64) {
      float s = us[tid] + us[tid + 64] + us[tid + 128] + us[tid + 192];
#pragma unroll
      for (int off = 32; off > 0; off >>= 1) s += __shfl_down(s, off);
      if (tid == 0) c0g[0] = s;
    }
  } else if (blk >= 16 && blk < 32) {
    // VhB[((ct*8+kk)*64 + lane)*8 + e] = f16(V[ct*16 + (lane&15)][kk*32 + (lane>>4)*8 + e])
    const int ct = blk - 16;
    const int kk = tid >> 7, rem = tid & 127;
    const int l = rem >> 1, e0 = (tid & 1) * 4;
    const float4 v4 = *(const float4*)&VA[(ct * 16 + (l & 15)) * 256 + kk * 32 + (l >> 4) * 8 + e0];
    __half* dst = VhB + ((size_t)(ct * 8 + kk) * 64 + l) * 8 + e0;
    *(__half2*)&dst[0] = __floats2half2_rn(v4.x, v4.y);
    *(__half2*)&dst[2] = __floats2half2_rn(v4.z, v4.w);
  }
  grid.sync();

  // ====== MFMA GEMM phase: Z = X*V, dots, out (A from XgA, no reg state) ===
  {
    const int w = tid >> 6, l = tid & 63;                 // wave / lane
    const int rt = w & 1, ctbase = (w >> 1) << 1;
    const int lm = l & 15, lh = l >> 4;
    if (tid < 256) ubuf[tid] = ub[tid];
    const float c0v = c0g[0];
    const __half* bp0 = VhB + (size_t)(ctbase * 8) * 512 + l * 8;        // ct0
    const __half* bp1 = VhB + (size_t)((ctbase + 1) * 8) * 512 + l * 8;  // ct1
    const int srow = rt * 16 + lm;

#pragma unroll 1
    for (int t = 0; t < 9; ++t) {
      const bool active = (blk != 0) && ((t < 8) || has9);
      const int gb = (blk != 0) ? ((t < 8) ? ((blk - 1) * 8 + t) : (2040 + (blk & 7))) : 0;
      __syncthreads();   // previous batch's xstage/redbuf fully consumed
      // ---- A-fragments: coalesced 1KB wave loads from XgA ----
      const __half* ap = XgA + (size_t)(gb * 2 + rt) * 4096 + l * 8;
      half8 afr[8];
#pragma unroll
      for (int kk = 0; kk < 8; ++kk)
        afr[kk] = *(const half8*)&ap[kk * 512];
      // stage to xstage (epilogue x-element reads) -- layout same as r8
#pragma unroll
      for (int kk = 0; kk < 8; ++kk)
        *(half8*)&xstage[srow][kk * 32 + lh * 8] = afr[kk];
      if (tid < 128) ((float*)redbuf)[tid] = 0.f;
      // ---- MFMA from registers: 2 tiles/wave, K=256 ----
      f32x4 z0 = {0.f, 0.f, 0.f, 0.f}, z1 = {0.f, 0.f, 0.f, 0.f};
#pragma unroll
      for (int kk = 0; kk < 8; ++kk) {
        const half8 b0 = *(const half8*)&bp0[kk * 512];
        const half8 b1 = *(const half8*)&bp1[kk * 512];
        z0 = __builtin_amdgcn_mfma_f32_16x16x32_f16(afr[kk], b0, z0, 0, 0, 0);
        z1 = __builtin_amdgcn_mfma_f32_16x16x32_f16(afr[kk], b1, z1, 0, 0, 0);
      }
      __syncthreads();   // xstage + redbuf ready
      // ---- epilogue: dp/dxx/dux over this wave's 32 cols ----
      float dp[4] = {}, dxx[4] = {}, dux[4] = {};
#pragma unroll
      for (int c = 0; c < 2; ++c) {
        const int col = (ctbase + c) * 16 + lm;
        const float uu = ubuf[col];
#pragma unroll
        for (int r = 0; r < 4; ++r) {
          const int s = rt * 16 + lh * 4 + r;
          const float xv = __half2float(xstage[s][col]);
          const float zz = (c == 0) ? z0[r] : z1[r];
          dp[r]  = fmaf(zz, xv, dp[r]);
          dxx[r] = fmaf(xv, xv, dxx[r]);
          dux[r] = fmaf(uu, xv, dux[r]);
        }
      }
#pragma unroll
      for (int off = 1; off < 16; off <<= 1)
#pragma unroll
        for (int r = 0; r < 4; ++r) {
          dp[r]  += __shfl_xor(dp[r], off);
          dxx[r] += __shfl_xor(dxx[r], off);
          dux[r] += __shfl_xor(dux[r], off);
        }
      if (lm == 0) {
#pragma unroll
        for (int r = 0; r < 4; ++r) {
          atomicAdd(&redbuf[rt][lh * 4 + r][0], dp[r]);
          atomicAdd(&redbuf[rt][lh * 4 + r][1], dxx[r]);
          atomicAdd(&redbuf[rt][lh * 4 + r][2], dux[r]);
        }
      }
      __syncthreads();
      if (active && tid < 32) {
        const int rr = tid >> 4, si = tid & 15;
        const float* rv = redbuf[rr][si];
        out[gb * 32 + rr * 16 + si] = 3.0f * rv[0] - rv[2] - 0.25f * c0v - rv[1];
      }
    }
  }
}

// ============================ launcher ======================================
extern "C" void kernel_launch(void* const* d_in, const int* in_sizes, int n_in,
                              void* d_out, int out_size, void* d_ws, size_t ws_size,
                              hipStream_t stream) {
  const float* E_ent   = (const float*)d_in[0];
  const float* E_rel   = (const float*)d_in[1];
  const float* W       = (const float*)d_in[2];
  const float* bvec    = (const float*)d_in[3];
  const int*   samples = (const int*)d_in[4];
  float* out = (float*)d_out;
  float* ws  = (float*)d_ws;

  float* VA = ws;                      // 65536 f32 (final V)
  float* VB = ws + 65536;              // NS scratch T
  float* VC = ws + 131072;             // NS intermediate
  float* ub = ws + 196608;             // 256
  float* c0 = ws + 196864;             // 1 (+pad)
  __half* VhB = (__half*)(ws + 197120);// 131072 f16 = 256 KB (fragment order)
  __half* XgA = (__half*)(ws + 262656);// 16.78M f16 = 33.5 MB (A fragments)

  void* args[] = {(void*)&E_ent, (void*)&E_rel, (void*)&W, (void*)&bvec,
                  (void*)&samples, (void*)&out, (void*)&VA, (void*)&VB,
                  (void*)&VC, (void*)&ub, (void*)&c0, (void*)&VhB, (void*)&XgA};
  hipLaunchCooperativeKernel((void*)fused_kernel, dim3(256), dim3(1024),
                             args, 0, stream);
}

// Round 10
// 871.102 us; speedup vs baseline: 1.2358x; 1.1337x over previous
//
#include <hip/hip_runtime.h>
#include <hip/hip_fp16.h>

typedef _Float16 half8 __attribute__((ext_vector_type(8)));
typedef float f32x4 __attribute__((ext_vector_type(4)));

// ---------------------------------------------------------------------------
// DistMultNN multi-kernel pipeline (MI355X), de-fused for per-phase rocprof
// attribution. out[s] = 3*x^T V x - (Vb).x - 0.25*(b^T V b) - x.x,
// x = r * circcorr(e1,e2), V = inv(W-I).
//   A: phase1_kernel  (256x1024)  GJ inverse on block 0 || cc->XgA on 1..255
//   B: ns_mt/ns_upd x2, compute_u, vhb_kernel   (small, ~5us each)
//   C: gemm_kernel    (2048x256, full occupancy) MFMA Z=X*V + epilogue -> out
// No cooperative launch: phases communicate through ws across kernel bounds.
// ---------------------------------------------------------------------------

#define ERS 268      // e1/e2 LDS row stride (floats)
#define XSS 280      // xstage row stride (halfs)

// ============ A: GJ (block 0) || cc+x -> XgA (blocks 1..255) ================
__global__ __launch_bounds__(1024, 4)
void phase1_kernel(const float* __restrict__ E_ent, const float* __restrict__ E_rel,
                   const float* __restrict__ W, const int* __restrict__ samples,
                   float* __restrict__ VA, __half* __restrict__ XgA) {
  __shared__ float regionY[17152];   // union: GJ rowbuf/colbuf | cc e1/e2 bufs
  const int tid = threadIdx.x;
  const int blk = blockIdx.x;

  if (blk == 0) {
    // ---- blocked in-place Gauss-Jordan (round-3 code, measured 355us) ----
    const int tx = tid & 31, ty = tid >> 5;
    const int r0 = ty << 3, gc0 = tx << 3;
    float (*rowbuf)[264] = (float(*)[264])&regionY[0];        // 8 x 264
    float (*colbuf)[8]   = (float(*)[8])&regionY[8 * 264];    // 256 x 8
    float gg[8][8];
#pragma unroll
    for (int i = 0; i < 8; ++i) {
      const float4 wa = *(const float4*)&W[(r0 + i) * 256 + gc0];
      const float4 wb = *(const float4*)&W[(r0 + i) * 256 + gc0 + 4];
      gg[i][0] = wa.x; gg[i][1] = wa.y; gg[i][2] = wa.z; gg[i][3] = wa.w;
      gg[i][4] = wb.x; gg[i][5] = wb.y; gg[i][6] = wb.z; gg[i][7] = wb.w;
#pragma unroll
      for (int j = 0; j < 8; ++j)
        if ((r0 + i) == (gc0 + j)) gg[i][j] -= 1.0f;
    }
    __syncthreads();
    for (int kg = 0; kg < 32; ++kg) {
      if (ty == kg) {
        const int L0 = (kg & 1) << 5;
#pragma unroll
        for (int kj = 0; kj < 8; ++kj) {
          float c[8];
#pragma unroll
          for (int i = 0; i < 8; ++i) c[i] = __shfl(gg[i][kj], L0 + kg, 64);
          const float pr = 1.0f / c[kj];
#pragma unroll
          for (int j = 0; j < 8; ++j) gg[kj][j] *= pr;
          if (tx == kg) gg[kj][kj] = pr;
#pragma unroll
          for (int i = 0; i < 8; ++i) {
            if (i == kj) continue;
#pragma unroll
            for (int j = 0; j < 8; ++j) gg[i][j] = fmaf(-c[i], gg[kj][j], gg[i][j]);
            if (tx == kg) gg[i][kj] = -c[i] * pr;
          }
        }
#pragma unroll
        for (int m = 0; m < 8; ++m) {
          float r4[8];
#pragma unroll
          for (int j = 0; j < 8; ++j)
            r4[j] = gg[m][j] + ((tx == kg && j == m) ? 1.0f : 0.0f);
          *(float4*)&rowbuf[m][gc0]     = make_float4(r4[0], r4[1], r4[2], r4[3]);
          *(float4*)&rowbuf[m][gc0 + 4] = make_float4(r4[4], r4[5], r4[6], r4[7]);
        }
      } else if (tx == kg) {
#pragma unroll
        for (int i = 0; i < 8; ++i) {
          *(float4*)&colbuf[r0 + i][0] = make_float4(gg[i][0], gg[i][1], gg[i][2], gg[i][3]);
          *(float4*)&colbuf[r0 + i][4] = make_float4(gg[i][4], gg[i][5], gg[i][6], gg[i][7]);
        }
      }
      __syncthreads();
      if (ty != kg) {
#pragma unroll
        for (int mp = 0; mp < 4; ++mp) {
          float ra[8], rb[8];
          {
            const float4 t0 = *(const float4*)&rowbuf[2 * mp][gc0];
            const float4 t1 = *(const float4*)&rowbuf[2 * mp][gc0 + 4];
            ra[0] = t0.x; ra[1] = t0.y; ra[2] = t0.z; ra[3] = t0.w;
            ra[4] = t1.x; ra[5] = t1.y; ra[6] = t1.z; ra[7] = t1.w;
            const float4 t2 = *(const float4*)&rowbuf[2 * mp + 1][gc0];
            const float4 t3 = *(const float4*)&rowbuf[2 * mp + 1][gc0 + 4];
            rb[0] = t2.x; rb[1] = t2.y; rb[2] = t2.z; rb[3] = t2.w;
            rb[4] = t3.x; rb[5] = t3.y; rb[6] = t3.z; rb[7] = t3.w;
          }
#pragma unroll
          for (int i = 0; i < 8; ++i) {
            const float2 fi = *(const float2*)&colbuf[r0 + i][2 * mp];
#pragma unroll
            for (int j = 0; j < 8; ++j) {
              gg[i][j] = fmaf(-fi.x, ra[j], gg[i][j]);
              gg[i][j] = fmaf(-fi.y, rb[j], gg[i][j]);
            }
          }
        }
      }
      __syncthreads();
    }
#pragma unroll
    for (int i = 0; i < 8; ++i) {
      *(float4*)&VA[(r0 + i) * 256 + gc0]     = make_float4(gg[i][0], gg[i][1], gg[i][2], gg[i][3]);
      *(float4*)&VA[(r0 + i) * 256 + gc0 + 4] = make_float4(gg[i][4], gg[i][5], gg[i][6], gg[i][7]);
    }
  } else {
    // ---- cc + x for up to 9 batches of 32 samples; x -> XgA (frag order) ---
    float (*e1buf)[ERS] = (float(*)[ERS])&regionY[0];
    float (*e2buf)[ERS] = (float(*)[ERS])&regionY[32 * ERS];
    const int g = tid & 31, l5 = tid >> 5, k0 = l5 << 3;
    const int ss = tid >> 5, f0 = (tid & 31) << 3;
    const int kkf = l5 >> 2, lhf = l5 & 3;
    const int rtf = g >> 4, lanef = (lhf << 4) | (g & 15);
    const bool has9 = (blk >= 248);
#pragma unroll 1
    for (int t = 0; t < 9; ++t) {
      if (t == 8 && !has9) break;
      const int gb = (t < 8) ? ((blk - 1) * 8 + t) : (2040 + (blk & 7));
      const int sb = gb << 5;
      __syncthreads();
      {
        const int ie1 = samples[(sb + ss) * 3 + 0];
        const int ie2 = samples[(sb + ss) * 3 + 2];
        const float* p1 = E_ent + (size_t)ie1 * 256 + f0;
        const float* p2 = E_ent + (size_t)ie2 * 256 + f0;
        *(float4*)&e1buf[ss][f0]     = *(const float4*)&p1[0];
        *(float4*)&e1buf[ss][f0 + 4] = *(const float4*)&p1[4];
        *(float4*)&e2buf[ss][f0]     = *(const float4*)&p2[0];
        *(float4*)&e2buf[ss][f0 + 4] = *(const float4*)&p2[4];
      }
      __syncthreads();
      float acc[8] = {};
#pragma unroll 2
      for (int j0 = 0; j0 < 256; j0 += 8) {
        float e1v[8], ew[16];
        {
          const float4 a = *(const float4*)&e1buf[g][j0];
          const float4 b = *(const float4*)&e1buf[g][j0 + 4];
          e1v[0] = a.x; e1v[1] = a.y; e1v[2] = a.z; e1v[3] = a.w;
          e1v[4] = b.x; e1v[5] = b.y; e1v[6] = b.z; e1v[7] = b.w;
        }
        const int h0 = (j0 + k0) & 255;
        const int h1 = (h0 + 8) & 255;
        {
          const float4 a = *(const float4*)&e2buf[g][h0];
          const float4 b = *(const float4*)&e2buf[g][h0 + 4];
          const float4 c = *(const float4*)&e2buf[g][h1];
          const float4 d = *(const float4*)&e2buf[g][h1 + 4];
          ew[0] = a.x;  ew[1] = a.y;  ew[2] = a.z;  ew[3] = a.w;
          ew[4] = b.x;  ew[5] = b.y;  ew[6] = b.z;  ew[7] = b.w;
          ew[8] = c.x;  ew[9] = c.y;  ew[10] = c.z; ew[11] = c.w;
          ew[12] = d.x; ew[13] = d.y; ew[14] = d.z; ew[15] = d.w;
        }
#pragma unroll
        for (int m = 0; m < 8; ++m)
#pragma unroll
          for (int jj = 0; jj < 8; ++jj)
            acc[m] = fmaf(e1v[jj], ew[jj + m], acc[m]);
      }
      const int ir = samples[(sb + g) * 3 + 1];
      const float* rp = E_rel + (size_t)ir * 256 + k0;
      const float4 r0v = *(const float4*)&rp[0];
      const float4 r1v = *(const float4*)&rp[4];
      union { __half2 h2[4]; uint4 u4; } cv;
      cv.h2[0] = __floats2half2_rn(r0v.x * acc[0], r0v.y * acc[1]);
      cv.h2[1] = __floats2half2_rn(r0v.z * acc[2], r0v.w * acc[3]);
      cv.h2[2] = __floats2half2_rn(r1v.x * acc[4], r1v.y * acc[5]);
      cv.h2[3] = __floats2half2_rn(r1v.z * acc[6], r1v.w * acc[7]);
      *(uint4*)&XgA[((size_t)((gb * 2 + rtf) * 8 + kkf) * 64 + lanef) * 8] = cv.u4;
    }
  }
}

// ============ B: Newton-Schulz polish (round-3 kernels, ~5us each) ==========
__global__ __launch_bounds__(64) void ns_mt_kernel(const float* __restrict__ W,
                                                   const float* __restrict__ Vin,
                                                   float* __restrict__ T) {
  const int bi = blockIdx.x >> 3, bj = blockIdx.x & 7;
  const int ti = threadIdx.x >> 3, tj = threadIdx.x & 7;
  const int i0 = bi * 32 + ti * 4, j0 = bj * 32 + tj * 4;
  float acc[4][4] = {};
  for (int k = 0; k < 256; ++k) {
    float4 a4 = *(const float4*)&W[k * 256 + i0];
    float a[4] = {a4.x, a4.y, a4.z, a4.w};
#pragma unroll
    for (int i = 0; i < 4; ++i) a[i] -= ((i0 + i) == k) ? 1.0f : 0.0f;
    float4 b4 = *(const float4*)&Vin[k * 256 + j0];
    const float b[4] = {b4.x, b4.y, b4.z, b4.w};
#pragma unroll
    for (int i = 0; i < 4; ++i)
#pragma unroll
      for (int j = 0; j < 4; ++j) acc[i][j] += a[i] * b[j];
  }
#pragma unroll
  for (int i = 0; i < 4; ++i)
    *(float4*)&T[(i0 + i) * 256 + j0] =
        make_float4(acc[i][0], acc[i][1], acc[i][2], acc[i][3]);
}

__global__ __launch_bounds__(64) void ns_upd_kernel(const float* __restrict__ Vin,
                                                    const float* __restrict__ T,
                                                    float* __restrict__ Vout) {
  const int bi = blockIdx.x >> 3, bj = blockIdx.x & 7;
  const int ti = threadIdx.x >> 3, tj = threadIdx.x & 7;
  const int i0 = bi * 32 + ti * 4, j0 = bj * 32 + tj * 4;
  float acc[4][4] = {};
  for (int k = 0; k < 256; ++k) {
    float a[4];
#pragma unroll
    for (int i = 0; i < 4; ++i) a[i] = Vin[(i0 + i) * 256 + k];
    float4 b4 = *(const float4*)&T[k * 256 + j0];
    const float b[4] = {b4.x, b4.y, b4.z, b4.w};
#pragma unroll
    for (int i = 0; i < 4; ++i)
#pragma unroll
      for (int j = 0; j < 4; ++j) acc[i][j] += a[i] * b[j];
  }
#pragma unroll
  for (int i = 0; i < 4; ++i) {
    float4 v = *(const float4*)&Vin[(i0 + i) * 256 + j0];
    *(float4*)&Vout[(i0 + i) * 256 + j0] =
        make_float4(2.0f * v.x - acc[i][0], 2.0f * v.y - acc[i][1],
                    2.0f * v.z - acc[i][2], 2.0f * v.w - acc[i][3]);
  }
}

__global__ __launch_bounds__(256) void compute_u_kernel(const float* __restrict__ V,
                                                        const float* __restrict__ b,
                                                        float* __restrict__ u,
                                                        float* __restrict__ c0) {
  const int tid = threadIdx.x;
  __shared__ float bs[256];
  __shared__ float us[256];
  bs[tid] = b[tid];
  __syncthreads();
  float acc = 0.0f;
  for (int j = 0; j < 256; j += 4) {
    float4 v4 = *(const float4*)&V[tid * 256 + j];
    acc += v4.x * bs[j] + v4.y * bs[j + 1] + v4.z * bs[j + 2] + v4.w * bs[j + 3];
  }
  u[tid] = acc;
  us[tid] = acc * bs[tid];
  __syncthreads();
  if (tid < 64) {
    float s = us[tid] + us[tid + 64] + us[tid + 128] + us[tid + 192];
#pragma unroll
    for (int off = 32; off > 0; off >>= 1) s += __shfl_down(s, off);
    if (tid == 0) c0[0] = s;
  }
}

// VhB[((ct*8+kk)*64 + lane)*8 + e] = f16(V[ct*16+(lane&15)][kk*32+(lane>>4)*8+e])
__global__ __launch_bounds__(1024) void vhb_kernel(const float* __restrict__ VA,
                                                   __half* __restrict__ VhB) {
  const int ct = blockIdx.x;
  const int tid = threadIdx.x;
  const int kk = tid >> 7, rem = tid & 127;
  const int l = rem >> 1, e0 = (tid & 1) * 4;
  const float4 v4 = *(const float4*)&VA[(ct * 16 + (l & 15)) * 256 + kk * 32 + (l >> 4) * 8 + e0];
  __half* dst = VhB + ((size_t)(ct * 8 + kk) * 64 + l) * 8 + e0;
  *(__half2*)&dst[0] = __floats2half2_rn(v4.x, v4.y);
  *(__half2*)&dst[2] = __floats2half2_rn(v4.z, v4.w);
}

// ============ C: MFMA GEMM + epilogue, one batch per block ==================
// 2048 blocks x 256 threads (4 waves). wave w: rt = w>>1 (sample half),
// ch = w&1 (col half, 8 ct each). Full-occupancy TLP hides XgA/VhB latency.
__global__ __launch_bounds__(256, 4)
void gemm_kernel(const __half* __restrict__ XgA, const __half* __restrict__ VhB,
                 const float* __restrict__ ub, const float* __restrict__ c0g,
                 float* __restrict__ out) {
  __shared__ __half xstage[32][XSS];
  __shared__ float ubuf[256];
  __shared__ float redbuf[2][16][4];

  const int tid = threadIdx.x;
  const int gb = blockIdx.x;
  const int w = tid >> 6, l = tid & 63;
  const int rt = w >> 1, ch = w & 1;
  const int lm = l & 15, lh = l >> 4;

  if (tid < 256) ubuf[tid] = ub[tid];
  if (tid < 128) ((float*)redbuf)[tid] = 0.f;

  // A-fragments (coalesced 1KB wave loads)
  const __half* ap = XgA + (size_t)(gb * 2 + rt) * 4096 + l * 8;
  half8 afr[8];
#pragma unroll
  for (int kk = 0; kk < 8; ++kk) afr[kk] = *(const half8*)&ap[kk * 512];
  if (ch == 0) {   // stage x for epilogue element reads (rows rt*16+lm)
#pragma unroll
    for (int kk = 0; kk < 8; ++kk)
      *(half8*)&xstage[rt * 16 + lm][kk * 32 + lh * 8] = afr[kk];
  }
  __syncthreads();

  // MFMA: 8 col-tiles per wave, K=256
  f32x4 z[8];
#pragma unroll
  for (int j = 0; j < 8; ++j) z[j] = (f32x4){0.f, 0.f, 0.f, 0.f};
#pragma unroll
  for (int kk = 0; kk < 8; ++kk) {
    half8 bfr[8];
#pragma unroll
    for (int j = 0; j < 8; ++j) {
      const int ct = ch * 8 + j;
      bfr[j] = *(const half8*)&VhB[((size_t)(ct * 8 + kk) * 64 + l) * 8];
    }
#pragma unroll
    for (int j = 0; j < 8; ++j)
      z[j] = __builtin_amdgcn_mfma_f32_16x16x32_f16(afr[kk], bfr[j], z[j], 0, 0, 0);
  }

  // epilogue: dp/dxx/dux; each (sample, col) touched by exactly one lane
  float dp[4] = {}, dxx[4] = {}, dux[4] = {};
#pragma unroll
  for (int j = 0; j < 8; ++j) {
    const int col = (ch * 8 + j) * 16 + lm;
    const float uu = ubuf[col];
#pragma unroll
    for (int r = 0; r < 4; ++r) {
      const int s = rt * 16 + lh * 4 + r;
      const float xv = __half2float(xstage[s][col]);
      dp[r]  = fmaf(z[j][r], xv, dp[r]);
      dxx[r] = fmaf(xv, xv, dxx[r]);
      dux[r] = fmaf(uu, xv, dux[r]);
    }
  }
#pragma unroll
  for (int off = 1; off < 16; off <<= 1)
#pragma unroll
    for (int r = 0; r < 4; ++r) {
      dp[r]  += __shfl_xor(dp[r], off);
      dxx[r] += __shfl_xor(dxx[r], off);
      dux[r] += __shfl_xor(dux[r], off);
    }
  if (lm == 0) {
#pragma unroll
    for (int r = 0; r < 4; ++r) {
      atomicAdd(&redbuf[rt][lh * 4 + r][0], dp[r]);
      atomicAdd(&redbuf[rt][lh * 4 + r][1], dxx[r]);
      atomicAdd(&redbuf[rt][lh * 4 + r][2], dux[r]);
    }
  }
  __syncthreads();
  if (tid < 32) {
    const float c0v = c0g[0];
    const int rr = tid >> 4, si = tid & 15;
    const float* rv = redbuf[rr][si];
    out[gb * 32 + rr * 16 + si] = 3.0f * rv[0] - rv[2] - 0.25f * c0v - rv[1];
  }
}

// ============================ launcher ======================================
extern "C" void kernel_launch(void* const* d_in, const int* in_sizes, int n_in,
                              void* d_out, int out_size, void* d_ws, size_t ws_size,
                              hipStream_t stream) {
  const float* E_ent   = (const float*)d_in[0];
  const float* E_rel   = (const float*)d_in[1];
  const float* W       = (const float*)d_in[2];
  const float* bvec    = (const float*)d_in[3];
  const int*   samples = (const int*)d_in[4];
  float* out = (float*)d_out;
  float* ws  = (float*)d_ws;

  float* VA = ws;                      // 65536 f32 (final V)
  float* VB = ws + 65536;              // NS scratch T
  float* VC = ws + 131072;             // NS intermediate
  float* ub = ws + 196608;             // 256
  float* c0 = ws + 196864;             // 1 (+pad)
  __half* VhB = (__half*)(ws + 197120);// 131072 f16 = 256 KB (fragment order)
  __half* XgA = (__half*)(ws + 262656);// 16.78M f16 = 33.5 MB (A fragments)

  phase1_kernel<<<256, 1024, 0, stream>>>(E_ent, E_rel, W, samples, VA, XgA);
  ns_mt_kernel<<<64, 64, 0, stream>>>(W, VA, VB);
  ns_upd_kernel<<<64, 64, 0, stream>>>(VA, VB, VC);
  ns_mt_kernel<<<64, 64, 0, stream>>>(W, VC, VB);
  ns_upd_kernel<<<64, 64, 0, stream>>>(VC, VB, VA);
  compute_u_kernel<<<1, 256, 0, stream>>>(VA, bvec, ub, c0);
  vhb_kernel<<<16, 1024, 0, stream>>>(VA, VhB);
  gemm_kernel<<<2048, 256, 0, stream>>>(XgA, VhB, ub, c0, out);
}

// Round 11
// 856.415 us; speedup vs baseline: 1.2569x; 1.0171x over previous
//
#include <hip/hip_runtime.h>
#include <hip/hip_fp16.h>

typedef _Float16 half8 __attribute__((ext_vector_type(8)));
typedef float f32x4 __attribute__((ext_vector_type(4)));

// ---------------------------------------------------------------------------
// DistMultNN multi-kernel pipeline (MI355X).
// out[s] = 3*x^T V x - (Vb).x - 0.25*(b^T V b) - x.x, x = r*circcorr(e1,e2)
//   A: phase1_kernel (511x1024): GJ inverse on block 0 || cc->XgA on 1..510
//      cc: XOR-swizzled LDS (T2, conflict-free b128) + rolling e2 window
//      (4 b128 / 64 FMA) + 2 blocks/CU.
//   B: ns_mt/ns_upd x2, compute_u, vhb_kernel (small)
//   C: gemm_kernel (2048x256) MFMA Z=X*V + epilogue -> out
// ---------------------------------------------------------------------------

#define XSS 280      // xstage row stride (halfs) in gemm kernel

// ============ A: GJ (block 0) || cc+x -> XgA (blocks 1..510) ================
__global__ __launch_bounds__(1024, 4)
void phase1_kernel(const float* __restrict__ E_ent, const float* __restrict__ E_rel,
                   const float* __restrict__ W, const int* __restrict__ samples,
                   float* __restrict__ VA, __half* __restrict__ XgA) {
  // union: GJ rowbuf/colbuf | cc e1buf(32x256 swz) + e2buf(32x256 swz) = 64KB
  __shared__ float regionY[16384];
  const int tid = threadIdx.x;
  const int blk = blockIdx.x;

  if (blk == 0) {
    // ---- blocked in-place Gauss-Jordan (round-3 code, measured ~355us) ----
    const int tx = tid & 31, ty = tid >> 5;
    const int r0 = ty << 3, gc0 = tx << 3;
    float (*rowbuf)[264] = (float(*)[264])&regionY[0];        // 8 x 264
    float (*colbuf)[8]   = (float(*)[8])&regionY[8 * 264];    // 256 x 8
    float gg[8][8];
#pragma unroll
    for (int i = 0; i < 8; ++i) {
      const float4 wa = *(const float4*)&W[(r0 + i) * 256 + gc0];
      const float4 wb = *(const float4*)&W[(r0 + i) * 256 + gc0 + 4];
      gg[i][0] = wa.x; gg[i][1] = wa.y; gg[i][2] = wa.z; gg[i][3] = wa.w;
      gg[i][4] = wb.x; gg[i][5] = wb.y; gg[i][6] = wb.z; gg[i][7] = wb.w;
#pragma unroll
      for (int j = 0; j < 8; ++j)
        if ((r0 + i) == (gc0 + j)) gg[i][j] -= 1.0f;
    }
    __syncthreads();
    for (int kg = 0; kg < 32; ++kg) {
      if (ty == kg) {
        const int L0 = (kg & 1) << 5;
#pragma unroll
        for (int kj = 0; kj < 8; ++kj) {
          float c[8];
#pragma unroll
          for (int i = 0; i < 8; ++i) c[i] = __shfl(gg[i][kj], L0 + kg, 64);
          const float pr = 1.0f / c[kj];
#pragma unroll
          for (int j = 0; j < 8; ++j) gg[kj][j] *= pr;
          if (tx == kg) gg[kj][kj] = pr;
#pragma unroll
          for (int i = 0; i < 8; ++i) {
            if (i == kj) continue;
#pragma unroll
            for (int j = 0; j < 8; ++j) gg[i][j] = fmaf(-c[i], gg[kj][j], gg[i][j]);
            if (tx == kg) gg[i][kj] = -c[i] * pr;
          }
        }
#pragma unroll
        for (int m = 0; m < 8; ++m) {
          float r4[8];
#pragma unroll
          for (int j = 0; j < 8; ++j)
            r4[j] = gg[m][j] + ((tx == kg && j == m) ? 1.0f : 0.0f);
          *(float4*)&rowbuf[m][gc0]     = make_float4(r4[0], r4[1], r4[2], r4[3]);
          *(float4*)&rowbuf[m][gc0 + 4] = make_float4(r4[4], r4[5], r4[6], r4[7]);
        }
      } else if (tx == kg) {
#pragma unroll
        for (int i = 0; i < 8; ++i) {
          *(float4*)&colbuf[r0 + i][0] = make_float4(gg[i][0], gg[i][1], gg[i][2], gg[i][3]);
          *(float4*)&colbuf[r0 + i][4] = make_float4(gg[i][4], gg[i][5], gg[i][6], gg[i][7]);
        }
      }
      __syncthreads();
      if (ty != kg) {
#pragma unroll
        for (int mp = 0; mp < 4; ++mp) {
          float ra[8], rb[8];
          {
            const float4 t0 = *(const float4*)&rowbuf[2 * mp][gc0];
            const float4 t1 = *(const float4*)&rowbuf[2 * mp][gc0 + 4];
            ra[0] = t0.x; ra[1] = t0.y; ra[2] = t0.z; ra[3] = t0.w;
            ra[4] = t1.x; ra[5] = t1.y; ra[6] = t1.z; ra[7] = t1.w;
            const float4 t2 = *(const float4*)&rowbuf[2 * mp + 1][gc0];
            const float4 t3 = *(const float4*)&rowbuf[2 * mp + 1][gc0 + 4];
            rb[0] = t2.x; rb[1] = t2.y; rb[2] = t2.z; rb[3] = t2.w;
            rb[4] = t3.x; rb[5] = t3.y; rb[6] = t3.z; rb[7] = t3.w;
          }
#pragma unroll
          for (int i = 0; i < 8; ++i) {
            const float2 fi = *(const float2*)&colbuf[r0 + i][2 * mp];
#pragma unroll
            for (int j = 0; j < 8; ++j) {
              gg[i][j] = fmaf(-fi.x, ra[j], gg[i][j]);
              gg[i][j] = fmaf(-fi.y, rb[j], gg[i][j]);
            }
          }
        }
      }
      __syncthreads();
    }
#pragma unroll
    for (int i = 0; i < 8; ++i) {
      *(float4*)&VA[(r0 + i) * 256 + gc0]     = make_float4(gg[i][0], gg[i][1], gg[i][2], gg[i][3]);
      *(float4*)&VA[(r0 + i) * 256 + gc0 + 4] = make_float4(gg[i][4], gg[i][5], gg[i][6], gg[i][7]);
    }
  } else {
    // ---- cc + x -> XgA. 4-5 batches of 32 samples per block. ----
    // LDS: e1buf = regionY[0..8191], e2buf = regionY[8192..16383].
    // Row g = 256 floats = 64 float4-units; unit u stored at u^(g&7) (T2).
    const int g = tid & 31, l5 = tid >> 5, k0 = l5 << 3;
    const int sw = g & 7;
    const int ss = tid >> 5;           // staging: sample row
    const int sws = ss & 7;
    const int uw0 = (tid & 31) << 1;   // staging: 2 units = 8 floats
    const int kkf = l5 >> 2, lhf = l5 & 3;
    const int rtf = g >> 4, lanef = (lhf << 4) | (g & 15);
    float* const e1w = &regionY[ss * 256];
    float* const e2w = &regionY[8192 + ss * 256];
    const float* const e1r = &regionY[g * 256];
    const float* const e2r = &regionY[8192 + g * 256];
    const int nb = (blk <= 8) ? 5 : 4;

    for (int t = 0; t < nb; ++t) {
      const int gb = (t < 4) ? ((blk - 1) * 4 + t) : (2040 + (blk - 1));
      const int sb = gb << 5;
      __syncthreads();   // previous batch's reads done before overwrite
      {  // stage 32 samples' e1,e2 rows, swizzled writes
        const int ie1 = samples[(sb + ss) * 3 + 0];
        const int ie2 = samples[(sb + ss) * 3 + 2];
        const float* p1 = E_ent + (size_t)ie1 * 256 + (uw0 << 2);
        const float* p2 = E_ent + (size_t)ie2 * 256 + (uw0 << 2);
        *(float4*)&e1w[((uw0 ^ sws) << 2)]       = *(const float4*)&p1[0];
        *(float4*)&e1w[(((uw0 + 1) ^ sws) << 2)] = *(const float4*)&p1[4];
        *(float4*)&e2w[((uw0 ^ sws) << 2)]       = *(const float4*)&p2[0];
        *(float4*)&e2w[(((uw0 + 1) ^ sws) << 2)] = *(const float4*)&p2[4];
      }
      __syncthreads();
      // ---- cc with rolling e2 window (4 b128 per 64 FMA) ----
      float acc[8] = {};
      float wlo[8], whi[8];
      {
        const int ul = k0 >> 2;
        const int uh = ((k0 + 8) & 255) >> 2;
        const float4 a = *(const float4*)&e2r[((ul ^ sw) << 2)];
        const float4 b = *(const float4*)&e2r[(((ul + 1) ^ sw) << 2)];
        const float4 c = *(const float4*)&e2r[((uh ^ sw) << 2)];
        const float4 d = *(const float4*)&e2r[(((uh + 1) ^ sw) << 2)];
        wlo[0] = a.x; wlo[1] = a.y; wlo[2] = a.z; wlo[3] = a.w;
        wlo[4] = b.x; wlo[5] = b.y; wlo[6] = b.z; wlo[7] = b.w;
        whi[0] = c.x; whi[1] = c.y; whi[2] = c.z; whi[3] = c.w;
        whi[4] = d.x; whi[5] = d.y; whi[6] = d.z; whi[7] = d.w;
      }
#pragma unroll 4
      for (int i = 0; i < 32; ++i) {
        float e1v[8];
        {
          const int u = i << 1;
          const float4 a = *(const float4*)&e1r[((u ^ sw) << 2)];
          const float4 b = *(const float4*)&e1r[(((u + 1) ^ sw) << 2)];
          e1v[0] = a.x; e1v[1] = a.y; e1v[2] = a.z; e1v[3] = a.w;
          e1v[4] = b.x; e1v[5] = b.y; e1v[6] = b.z; e1v[7] = b.w;
        }
        float wnx[8];
        {
          const int hn = ((i << 3) + k0 + 16) & 255;
          const int u = hn >> 2;
          const float4 a = *(const float4*)&e2r[((u ^ sw) << 2)];
          const float4 b = *(const float4*)&e2r[(((u + 1) ^ sw) << 2)];
          wnx[0] = a.x; wnx[1] = a.y; wnx[2] = a.z; wnx[3] = a.w;
          wnx[4] = b.x; wnx[5] = b.y; wnx[6] = b.z; wnx[7] = b.w;
        }
#pragma unroll
        for (int m = 0; m < 8; ++m) {
#pragma unroll
          for (int jj = 0; jj < 8; ++jj) {
            const int idx = jj + m;
            const float wv = (idx < 8) ? wlo[idx] : whi[idx - 8];
            acc[m] = fmaf(e1v[jj], wv, acc[m]);
          }
        }
#pragma unroll
        for (int q = 0; q < 8; ++q) { wlo[q] = whi[q]; whi[q] = wnx[q]; }
      }
      // x = r * cc -> XgA in MFMA A-fragment order
      const int ir = samples[(sb + g) * 3 + 1];
      const float* rp = E_rel + (size_t)ir * 256 + k0;
      const float4 r0v = *(const float4*)&rp[0];
      const float4 r1v = *(const float4*)&rp[4];
      union { __half2 h2[4]; uint4 u4; } cv;
      cv.h2[0] = __floats2half2_rn(r0v.x * acc[0], r0v.y * acc[1]);
      cv.h2[1] = __floats2half2_rn(r0v.z * acc[2], r0v.w * acc[3]);
      cv.h2[2] = __floats2half2_rn(r1v.x * acc[4], r1v.y * acc[5]);
      cv.h2[3] = __floats2half2_rn(r1v.z * acc[6], r1v.w * acc[7]);
      *(uint4*)&XgA[((size_t)((gb * 2 + rtf) * 8 + kkf) * 64 + lanef) * 8] = cv.u4;
    }
  }
}

// ============ B: Newton-Schulz polish + u + VhB (unchanged) =================
__global__ __launch_bounds__(64) void ns_mt_kernel(const float* __restrict__ W,
                                                   const float* __restrict__ Vin,
                                                   float* __restrict__ T) {
  const int bi = blockIdx.x >> 3, bj = blockIdx.x & 7;
  const int ti = threadIdx.x >> 3, tj = threadIdx.x & 7;
  const int i0 = bi * 32 + ti * 4, j0 = bj * 32 + tj * 4;
  float acc[4][4] = {};
  for (int k = 0; k < 256; ++k) {
    float4 a4 = *(const float4*)&W[k * 256 + i0];
    float a[4] = {a4.x, a4.y, a4.z, a4.w};
#pragma unroll
    for (int i = 0; i < 4; ++i) a[i] -= ((i0 + i) == k) ? 1.0f : 0.0f;
    float4 b4 = *(const float4*)&Vin[k * 256 + j0];
    const float b[4] = {b4.x, b4.y, b4.z, b4.w};
#pragma unroll
    for (int i = 0; i < 4; ++i)
#pragma unroll
      for (int j = 0; j < 4; ++j) acc[i][j] += a[i] * b[j];
  }
#pragma unroll
  for (int i = 0; i < 4; ++i)
    *(float4*)&T[(i0 + i) * 256 + j0] =
        make_float4(acc[i][0], acc[i][1], acc[i][2], acc[i][3]);
}

__global__ __launch_bounds__(64) void ns_upd_kernel(const float* __restrict__ Vin,
                                                    const float* __restrict__ T,
                                                    float* __restrict__ Vout) {
  const int bi = blockIdx.x >> 3, bj = blockIdx.x & 7;
  const int ti = threadIdx.x >> 3, tj = threadIdx.x & 7;
  const int i0 = bi * 32 + ti * 4, j0 = bj * 32 + tj * 4;
  float acc[4][4] = {};
  for (int k = 0; k < 256; ++k) {
    float a[4];
#pragma unroll
    for (int i = 0; i < 4; ++i) a[i] = Vin[(i0 + i) * 256 + k];
    float4 b4 = *(const float4*)&T[k * 256 + j0];
    const float b[4] = {b4.x, b4.y, b4.z, b4.w};
#pragma unroll
    for (int i = 0; i < 4; ++i)
#pragma unroll
      for (int j = 0; j < 4; ++j) acc[i][j] += a[i] * b[j];
  }
#pragma unroll
  for (int i = 0; i < 4; ++i) {
    float4 v = *(const float4*)&Vin[(i0 + i) * 256 + j0];
    *(float4*)&Vout[(i0 + i) * 256 + j0] =
        make_float4(2.0f * v.x - acc[i][0], 2.0f * v.y - acc[i][1],
                    2.0f * v.z - acc[i][2], 2.0f * v.w - acc[i][3]);
  }
}

__global__ __launch_bounds__(256) void compute_u_kernel(const float* __restrict__ V,
                                                        const float* __restrict__ b,
                                                        float* __restrict__ u,
                                                        float* __restrict__ c0) {
  const int tid = threadIdx.x;
  __shared__ float bs[256];
  __shared__ float us[256];
  bs[tid] = b[tid];
  __syncthreads();
  float acc = 0.0f;
  for (int j = 0; j < 256; j += 4) {
    float4 v4 = *(const float4*)&V[tid * 256 + j];
    acc += v4.x * bs[j] + v4.y * bs[j + 1] + v4.z * bs[j + 2] + v4.w * bs[j + 3];
  }
  u[tid] = acc;
  us[tid] = acc * bs[tid];
  __syncthreads();
  if (tid < 64) {
    float s = us[tid] + us[tid + 64] + us[tid + 128] + us[tid + 192];
#pragma unroll
    for (int off = 32; off > 0; off >>= 1) s += __shfl_down(s, off);
    if (tid == 0) c0[0] = s;
  }
}

__global__ __launch_bounds__(1024) void vhb_kernel(const float* __restrict__ VA,
                                                   __half* __restrict__ VhB) {
  const int ct = blockIdx.x;
  const int tid = threadIdx.x;
  const int kk = tid >> 7, rem = tid & 127;
  const int l = rem >> 1, e0 = (tid & 1) * 4;
  const float4 v4 = *(const float4*)&VA[(ct * 16 + (l & 15)) * 256 + kk * 32 + (l >> 4) * 8 + e0];
  __half* dst = VhB + ((size_t)(ct * 8 + kk) * 64 + l) * 8 + e0;
  *(__half2*)&dst[0] = __floats2half2_rn(v4.x, v4.y);
  *(__half2*)&dst[2] = __floats2half2_rn(v4.z, v4.w);
}

// ============ C: MFMA GEMM + epilogue, one batch per block (unchanged) ======
__global__ __launch_bounds__(256, 4)
void gemm_kernel(const __half* __restrict__ XgA, const __half* __restrict__ VhB,
                 const float* __restrict__ ub, const float* __restrict__ c0g,
                 float* __restrict__ out) {
  __shared__ __half xstage[32][XSS];
  __shared__ float ubuf[256];
  __shared__ float redbuf[2][16][4];

  const int tid = threadIdx.x;
  const int gb = blockIdx.x;
  const int w = tid >> 6, l = tid & 63;
  const int rt = w >> 1, ch = w & 1;
  const int lm = l & 15, lh = l >> 4;

  if (tid < 256) ubuf[tid] = ub[tid];
  if (tid < 128) ((float*)redbuf)[tid] = 0.f;

  const __half* ap = XgA + (size_t)(gb * 2 + rt) * 4096 + l * 8;
  half8 afr[8];
#pragma unroll
  for (int kk = 0; kk < 8; ++kk) afr[kk] = *(const half8*)&ap[kk * 512];
  if (ch == 0) {
#pragma unroll
    for (int kk = 0; kk < 8; ++kk)
      *(half8*)&xstage[rt * 16 + lm][kk * 32 + lh * 8] = afr[kk];
  }
  __syncthreads();

  f32x4 z[8];
#pragma unroll
  for (int j = 0; j < 8; ++j) z[j] = (f32x4){0.f, 0.f, 0.f, 0.f};
#pragma unroll
  for (int kk = 0; kk < 8; ++kk) {
    half8 bfr[8];
#pragma unroll
    for (int j = 0; j < 8; ++j) {
      const int ct = ch * 8 + j;
      bfr[j] = *(const half8*)&VhB[((size_t)(ct * 8 + kk) * 64 + l) * 8];
    }
#pragma unroll
    for (int j = 0; j < 8; ++j)
      z[j] = __builtin_amdgcn_mfma_f32_16x16x32_f16(afr[kk], bfr[j], z[j], 0, 0, 0);
  }

  float dp[4] = {}, dxx[4] = {}, dux[4] = {};
#pragma unroll
  for (int j = 0; j < 8; ++j) {
    const int col = (ch * 8 + j) * 16 + lm;
    const float uu = ubuf[col];
#pragma unroll
    for (int r = 0; r < 4; ++r) {
      const int s = rt * 16 + lh * 4 + r;
      const float xv = __half2float(xstage[s][col]);
      dp[r]  = fmaf(z[j][r], xv, dp[r]);
      dxx[r] = fmaf(xv, xv, dxx[r]);
      dux[r] = fmaf(uu, xv, dux[r]);
    }
  }
#pragma unroll
  for (int off = 1; off < 16; off <<= 1)
#pragma unroll
    for (int r = 0; r < 4; ++r) {
      dp[r]  += __shfl_xor(dp[r], off);
      dxx[r] += __shfl_xor(dxx[r], off);
      dux[r] += __shfl_xor(dux[r], off);
    }
  if (lm == 0) {
#pragma unroll
    for (int r = 0; r < 4; ++r) {
      atomicAdd(&redbuf[rt][lh * 4 + r][0], dp[r]);
      atomicAdd(&redbuf[rt][lh * 4 + r][1], dxx[r]);
      atomicAdd(&redbuf[rt][lh * 4 + r][2], dux[r]);
    }
  }
  __syncthreads();
  if (tid < 32) {
    const float c0v = c0g[0];
    const int rr = tid >> 4, si = tid & 15;
    const float* rv = redbuf[rr][si];
    out[gb * 32 + rr * 16 + si] = 3.0f * rv[0] - rv[2] - 0.25f * c0v - rv[1];
  }
}

// ============================ launcher ======================================
extern "C" void kernel_launch(void* const* d_in, const int* in_sizes, int n_in,
                              void* d_out, int out_size, void* d_ws, size_t ws_size,
                              hipStream_t stream) {
  const float* E_ent   = (const float*)d_in[0];
  const float* E_rel   = (const float*)d_in[1];
  const float* W       = (const float*)d_in[2];
  const float* bvec    = (const float*)d_in[3];
  const int*   samples = (const int*)d_in[4];
  float* out = (float*)d_out;
  float* ws  = (float*)d_ws;

  float* VA = ws;                      // 65536 f32 (final V)
  float* VB = ws + 65536;              // NS scratch T
  float* VC = ws + 131072;             // NS intermediate
  float* ub = ws + 196608;             // 256
  float* c0 = ws + 196864;             // 1 (+pad)
  __half* VhB = (__half*)(ws + 197120);// 131072 f16 = 256 KB (fragment order)
  __half* XgA = (__half*)(ws + 262656);// 16.78M f16 = 33.5 MB (A fragments)

  phase1_kernel<<<511, 1024, 0, stream>>>(E_ent, E_rel, W, samples, VA, XgA);
  ns_mt_kernel<<<64, 64, 0, stream>>>(W, VA, VB);
  ns_upd_kernel<<<64, 64, 0, stream>>>(VA, VB, VC);
  ns_mt_kernel<<<64, 64, 0, stream>>>(W, VC, VB);
  ns_upd_kernel<<<64, 64, 0, stream>>>(VC, VB, VA);
  compute_u_kernel<<<1, 256, 0, stream>>>(VA, bvec, ub, c0);
  vhb_kernel<<<16, 1024, 0, stream>>>(VA, VhB);
  gemm_kernel<<<2048, 256, 0, stream>>>(XgA, VhB, ub, c0, out);
}